// Round 5
// baseline (214.457 us; speedup 1.0000x reference)
//
#include <hip/hip_runtime.h>
#include <hip/hip_bf16.h>

#define B_ 4
#define T_ 2048
#define C_ 1024
#define H_ 16
#define HD_ 64
#define M_ (B_*T_)        // 8192 rows
#define N3_ (3*C_)        // 3072
#define QKVSZ (B_*H_*T_*HD_)  // 8388608 elems per tensor
#define QSCALE 0.1803368801f  // 0.125 * log2(e)

typedef unsigned short u16;
typedef unsigned int u32;
typedef __attribute__((ext_vector_type(8))) __bf16 bf16x8;
typedef __attribute__((ext_vector_type(4))) float f32x4;
typedef __attribute__((ext_vector_type(16))) float f32x16;
typedef __attribute__((ext_vector_type(2))) int i32x2;
typedef __attribute__((ext_vector_type(4))) u32 u32x4;
typedef const __attribute__((address_space(1))) void* gptr_t;
typedef __attribute__((address_space(3))) void* sptr_t;

__device__ __forceinline__ u16 f2b(float f) {
  __hip_bfloat16 h = __float2bfloat16(f);
  return __builtin_bit_cast(u16, h);
}

// v_cvt_pk_bf16_f32: lo -> bits[15:0], hi -> bits[31:16]
__device__ __forceinline__ u32 cvtpk(float lo, float hi) {
  u32 r;
  asm volatile("v_cvt_pk_bf16_f32 %0, %1, %2" : "=v"(r) : "v"(lo), "v"(hi));
  return r;
}

// ---------------- fp32 -> bf16 convert (vectorized) ----------------
__global__ __launch_bounds__(256) void cvt_kernel(const float* __restrict__ src,
                                                  u16* __restrict__ dst, int n4) {
  int i = blockIdx.x * blockDim.x + threadIdx.x;
  int stride = gridDim.x * blockDim.x;
  for (; i < n4; i += stride) {
    float4 f = ((const float4*)src)[i];
    ushort4 o;
    o.x = f2b(f.x); o.y = f2b(f.y); o.z = f2b(f.z); o.w = f2b(f.w);
    ((ushort4*)dst)[i] = o;
  }
}

// ---------------- transpose + convert: src[K][N] fp32 -> dst[N][K] bf16 ----------------
__global__ __launch_bounds__(256) void tr_cvt(const float* __restrict__ src,
                                              u16* __restrict__ dst, int K, int N) {
  __shared__ u16 tile[64][72];   // +8 pad
  int k0 = blockIdx.x * 64, n0 = blockIdx.y * 64;
  #pragma unroll
  for (int t = 0; t < 16; ++t) {
    int idx = threadIdx.x + t * 256;
    int r = idx >> 6, c = idx & 63;
    tile[r][c] = f2b(src[(size_t)(k0 + r) * N + n0 + c]);
  }
  __syncthreads();
  #pragma unroll
  for (int t = 0; t < 16; ++t) {
    int idx = threadIdx.x + t * 256;
    int r = idx >> 6, c = idx & 63;       // r = local n, c = local k
    dst[(size_t)(n0 + r) * K + k0 + c] = tile[c][r];
  }
}

// ---------------- GEMM: C[M][N] = A[M][K] * Bt[N][K]^T + bias ----------------
// BM=256 x BN=128, BK=32, 4 waves each owning 128x64 (acc 8x4).
// Double-buffered LDS; stage(t+1) issued BEFORE compute of t (T3-minimum).
// Granule-XOR swizzle (g ^= (row>>1)&3) via pre-swizzled global source +
// swizzled ds_read (both-sides). XCD-aware block swizzle (grids %8==0).
// EPI 0: scatter to q (scaled) / k / v^T.  EPI 1: fp32 out [M][N].
template <int EPI>
__global__ __launch_bounds__(256, 2) void gemm_bt(const u16* __restrict__ A,
                                                  const u16* __restrict__ Bt,
                                                  const float* __restrict__ bias,
                                                  int K, int N,
                                                  u16* __restrict__ out_qkv,
                                                  float* __restrict__ out_f) {
  __shared__ __align__(16) u16 As[2][256 * 32];
  __shared__ __align__(16) u16 Bs[2][128 * 32];
  const int tid = threadIdx.x;
  const int wave = tid >> 6, lane = tid & 63;
  const int lr = lane & 15, lk = lane >> 4;

  // XCD-aware swizzle (bijective: nwg % 8 == 0 for both grids)
  const int gx = gridDim.x;
  const int nwg = gx * gridDim.y;
  const int wg = blockIdx.x + gx * blockIdx.y;
  const int cpx = nwg >> 3;
  const int swz = (wg & 7) * cpx + (wg >> 3);
  const int m0 = (swz % gx) * 256, n0 = (swz / gx) * 128;
  const int wr = (wave >> 1) * 128, wc = (wave & 1) * 64;

  f32x4 acc[8][4] = {};

  auto stage = [&](int buf, int it) {
    const int kt = it * 32;
    #pragma unroll
    for (int i = 0; i < 4; ++i) {                // A: 1024 chunks / 256 thr
      int ch = i * 256 + wave * 64 + lane;
      int row = ch >> 2;
      int gsrc = (ch & 3) ^ ((row >> 1) & 3);
      __builtin_amdgcn_global_load_lds((gptr_t)(A + (size_t)(m0 + row) * K + kt + gsrc * 8),
                                       (sptr_t)(&As[buf][ch * 8]), 16, 0, 0);
    }
    #pragma unroll
    for (int i = 0; i < 2; ++i) {                // B: 512 chunks / 256 thr
      int ch = i * 256 + wave * 64 + lane;
      int row = ch >> 2;
      int gsrc = (ch & 3) ^ ((row >> 1) & 3);
      __builtin_amdgcn_global_load_lds((gptr_t)(Bt + (size_t)(n0 + row) * K + kt + gsrc * 8),
                                       (sptr_t)(&Bs[buf][ch * 8]), 16, 0, 0);
    }
  };

  const int KI = K / 32;
  stage(0, 0);
  __syncthreads();

  for (int it = 0; it < KI; ++it) {
    const int cur = it & 1;
    if (it + 1 < KI) stage(cur ^ 1, it + 1);     // prefetch overlaps this tile's compute

    bf16x8 af[8], bfr[4];
    #pragma unroll
    for (int mi = 0; mi < 8; ++mi) {
      int r = wr + mi * 16 + lr;
      af[mi] = *(const bf16x8*)(&As[cur][r * 32 + ((lk ^ ((r >> 1) & 3)) << 3)]);
    }
    #pragma unroll
    for (int ni = 0; ni < 4; ++ni) {
      int r = wc + ni * 16 + lr;
      bfr[ni] = *(const bf16x8*)(&Bs[cur][r * 32 + ((lk ^ ((r >> 1) & 3)) << 3)]);
    }
    #pragma unroll
    for (int mi = 0; mi < 8; ++mi)
      #pragma unroll
      for (int ni = 0; ni < 4; ++ni)
        acc[mi][ni] = __builtin_amdgcn_mfma_f32_16x16x32_bf16(af[mi], bfr[ni], acc[mi][ni], 0, 0, 0);
    __syncthreads();                              // also drains prefetch vmcnt
  }

  if (EPI == 0) {
    const int sel = (n0 >> 10);                   // whole block same q/k/v segment
    #pragma unroll
    for (int mi = 0; mi < 8; ++mi) {
      #pragma unroll
      for (int ni = 0; ni < 4; ++ni) {
        int m = m0 + wr + mi * 16 + lk * 4;       // +j
        int n = n0 + wc + ni * 16 + lr;
        int rem = n & 1023, h = rem >> 6, d = rem & 63;
        int b = m >> 11, t = m & 2047;
        if (sel == 2) {                           // v^T: t contiguous -> ushort4
          ushort4 st;
          #pragma unroll
          for (int j = 0; j < 4; ++j)
            ((u16*)&st)[j] = f2b(acc[mi][ni][j] + bias[n]);
          *(ushort4*)(out_qkv + 2 * (size_t)QKVSZ +
                      (((size_t)(b * H_ + h) * HD_ + d) * T_ + t)) = st;
        } else {
          #pragma unroll
          for (int j = 0; j < 4; ++j) {
            float val = acc[mi][ni][j] + bias[n];
            if (sel == 0) val *= QSCALE;
            out_qkv[(size_t)sel * QKVSZ +
                    (((size_t)(b * H_ + h) * T_ + (t + j)) * HD_ + d)] = f2b(val);
          }
        }
      }
    }
  } else {
    #pragma unroll
    for (int mi = 0; mi < 8; ++mi)
      #pragma unroll
      for (int ni = 0; ni < 4; ++ni)
        #pragma unroll
        for (int j = 0; j < 4; ++j) {
          int m = m0 + wr + mi * 16 + lk * 4 + j;
          int n = n0 + wc + ni * 16 + lr;
          out_f[(size_t)m * C_ + n] = acc[mi][ni][j] + bias[n];
        }
  }
}

// ---------------- causal flash attention ----------------
// 128 threads = 2 waves; q-tile 64 (wave w owns q-rows [BQ+32w, BQ+32w+32)).
// grid (bh=64, 32 q-tiles) = 2048 blocks, heavy-first. 32x32x16 MFMAs,
// swapped S^T = mfma(K,Q). Softmax per-lane + 1 shfl_xor(32). P in registers
// via cvt_pk + permlane32_swap. O^T = mfma(Vt, P). K/V dbuf + prefetch.
__global__ __launch_bounds__(128, 2) void attn_k(const u16* __restrict__ q,
                                                 const u16* __restrict__ k,
                                                 const u16* __restrict__ vt,
                                                 u16* __restrict__ y) {
  __shared__ __align__(16) u16 Ks[2][64 * 64];
  __shared__ __align__(16) u16 Vs[2][64 * 64];
  const int tid = threadIdx.x;
  const int wave = tid >> 6, lane = tid & 63;
  const int hi = lane >> 5, lq = lane & 31;
  const int qtb = gridDim.y - 1 - blockIdx.y;    // 31..0, heavy first
  const int bh = blockIdx.x;                     // fastest dim -> XCD spread
  const size_t koff = (size_t)bh * T_ * HD_;     // q,k: [bh][t][d]
  const size_t voff = (size_t)bh * HD_ * T_;     // vt:  [bh][d][t]
  const int qrow = qtb * 64 + 32 * wave + lq;    // this lane's q row (global)

  // Q B-frags (pre-scaled by 0.125*log2e): qf[c] = Q[qrow][16c+8hi .. +8]
  bf16x8 qf[4];
  #pragma unroll
  for (int c = 0; c < 4; ++c)
    qf[c] = *(const bf16x8*)(q + koff + (size_t)qrow * HD_ + 16 * c + 8 * hi);

  f32x16 o[2] = {};                              // [dh]: O^T rows 32dh..
  float mrun = -1e30f, lsum = 0.f;

  auto stage = [&](int buf, int kt) {
    const u16* kb = k + koff + (size_t)kt * 64 * HD_;
    const u16* vb = vt + voff + (size_t)kt * 64;
    #pragma unroll
    for (int j = 0; j < 4; ++j) {
      int cb = j * 128 + wave * 64;              // wave-uniform chunk base
      int ch = cb + lane;
      int row = ch >> 3, gg = ch & 7;
      int src = gg ^ (row & 7);                  // pre-swizzled global source
      __builtin_amdgcn_global_load_lds((gptr_t)(kb + row * HD_ + src * 8),
                                       (sptr_t)(&Ks[buf][cb * 8]), 16, 0, 0);
      __builtin_amdgcn_global_load_lds((gptr_t)(vb + (size_t)row * T_ + src * 8),
                                       (sptr_t)(&Vs[buf][cb * 8]), 16, 0, 0);
    }
  };

  const int nt = qtb + 1;
  stage(0, 0);
  __syncthreads();

  for (int kt = 0; kt < nt; ++kt) {
    const int cur = kt & 1;
    if (kt + 1 < nt) stage(cur ^ 1, kt + 1);
    const bool dia = (kt == qtb);
    const bool skip1 = dia && (wave == 0);       // kh=1 fully masked (wave-uniform)
    const u16* Kb = &Ks[cur][0];
    const u16* Vb = &Vs[cur][0];

    // ---- S^T = K Q^T ----
    f32x16 s[2] = {};
    #pragma unroll
    for (int c = 0; c < 4; ++c) {
      #pragma unroll
      for (int kh = 0; kh < 2; ++kh) {
        if (kh == 1 && skip1) continue;
        int row = 32 * kh + lq;
        bf16x8 kf = *(const bf16x8*)(Kb + row * 64 + (((2 * c + hi) ^ (row & 7)) << 3));
        s[kh] = __builtin_amdgcn_mfma_f32_32x32x16_bf16(kf, qf[c], s[kh], 0, 0, 0);
      }
    }

    if (dia) {
      // wave 0: kh0 diagonal-masked; wave 1: kh0 fully visible, kh1 diagonal-masked
      #pragma unroll
      for (int rr = 0; rr < 16; ++rr) {
        int kg = 64 * kt + 4 * hi + (rr & 3) + 8 * (rr >> 2);
        if (wave == 0) { if (kg > qrow) s[0][rr] = -1e30f; }
        else           { if (kg + 32 > qrow) s[1][rr] = -1e30f; }
      }
    }

    // ---- online softmax (lane and lane^32 share a q-row) ----
    float tm = -1e30f;
    #pragma unroll
    for (int kh = 0; kh < 2; ++kh) {
      if (kh == 1 && skip1) continue;
      #pragma unroll
      for (int rr = 0; rr < 16; ++rr) tm = fmaxf(tm, s[kh][rr]);
    }
    tm = fmaxf(tm, __shfl_xor(tm, 32));
    if (__any(tm > mrun + 8.f)) {                // defer-max (T13)
      float mn = fmaxf(mrun, tm);
      float al = exp2f(mrun - mn);
      lsum *= al;
      o[0] *= al;
      o[1] *= al;
      mrun = mn;
    }
    float rs = 0.f;
    #pragma unroll
    for (int kh = 0; kh < 2; ++kh) {
      if (kh == 1 && skip1) continue;
      #pragma unroll
      for (int rr = 0; rr < 16; ++rr) {
        float p = exp2f(s[kh][rr] - mrun);
        s[kh][rr] = p;
        rs += p;
      }
    }
    rs += __shfl_xor(rs, 32);
    lsum += rs;

    // ---- PV: O^T[d][q] += Vt P (P assembled in-register) ----
    #pragma unroll
    for (int kh = 0; kh < 2; ++kh) {
      if (kh == 1 && skip1) continue;
      bf16x8 pf[2];
      #pragma unroll
      for (int ct = 0; ct < 2; ++ct) {
        u32 A0 = cvtpk(s[kh][8 * ct + 0], s[kh][8 * ct + 1]);
        u32 A1 = cvtpk(s[kh][8 * ct + 2], s[kh][8 * ct + 3]);
        u32 B0 = cvtpk(s[kh][8 * ct + 4], s[kh][8 * ct + 5]);
        u32 B1 = cvtpk(s[kh][8 * ct + 6], s[kh][8 * ct + 7]);
        i32x2 r0 = __builtin_amdgcn_permlane32_swap((int)A0, (int)B0, false, false);
        i32x2 r1 = __builtin_amdgcn_permlane32_swap((int)A1, (int)B1, false, false);
        u32x4 w = {(u32)r0[0], (u32)r1[0], (u32)r0[1], (u32)r1[1]};
        pf[ct] = __builtin_bit_cast(bf16x8, w);
      }
      #pragma unroll
      for (int ct = 0; ct < 2; ++ct)
        #pragma unroll
        for (int dh = 0; dh < 2; ++dh) {
          int row = 32 * dh + lq;
          bf16x8 vf = *(const bf16x8*)(Vb + row * 64 + (((4 * kh + 2 * ct + hi) ^ (row & 7)) << 3));
          o[dh] = __builtin_amdgcn_mfma_f32_32x32x16_bf16(vf, pf[ct], o[dh], 0, 0, 0);
        }
    }
    __syncthreads();
  }

  // ---- epilogue: y[b,t,h*64+d] = O^T[d][q] / l ----
  const int b = bh >> 4, h = bh & 15;
  float li = 1.0f / lsum;
  u16* yrow = y + (size_t)(b * T_ + qrow) * C_ + h * 64;
  #pragma unroll
  for (int dh = 0; dh < 2; ++dh)
    #pragma unroll
    for (int u = 0; u < 4; ++u) {
      ushort4 st;
      st.x = f2b(o[dh][4 * u + 0] * li);
      st.y = f2b(o[dh][4 * u + 1] * li);
      st.z = f2b(o[dh][4 * u + 2] * li);
      st.w = f2b(o[dh][4 * u + 3] * li);
      *(ushort4*)(yrow + 32 * dh + 8 * u + 4 * hi) = st;
    }
}

extern "C" void kernel_launch(void* const* d_in, const int* in_sizes, int n_in,
                              void* d_out, int out_size, void* d_ws, size_t ws_size,
                              hipStream_t stream) {
  const float* x      = (const float*)d_in[0];
  const float* W_attn = (const float*)d_in[1];
  const float* b_attn = (const float*)d_in[2];
  const float* W_proj = (const float*)d_in[3];
  const float* b_proj = (const float*)d_in[4];
  float* out = (float*)d_out;

  u16* ws = (u16*)d_ws;
  u16* xb  = ws;
  u16* Wat = xb + (size_t)M_ * C_;
  u16* Wpt = Wat + (size_t)N3_ * C_;
  u16* qkv = Wpt + (size_t)C_ * C_;
  u16* y   = qkv + (size_t)3 * QKVSZ;

  cvt_kernel<<<2048, 256, 0, stream>>>(x, xb, M_ * C_ / 4);
  tr_cvt<<<dim3(C_ / 64, N3_ / 64), 256, 0, stream>>>(W_attn, Wat, C_, N3_);
  tr_cvt<<<dim3(C_ / 64, C_ / 64), 256, 0, stream>>>(W_proj, Wpt, C_, C_);
  gemm_bt<0><<<dim3(M_ / 256, N3_ / 128), 256, 0, stream>>>(xb, Wat, b_attn, C_, N3_, qkv, nullptr);
  attn_k<<<dim3(B_ * H_, T_ / 64), 128, 0, stream>>>(qkv, qkv + QKVSZ, qkv + 2 * QKVSZ, y);
  gemm_bt<1><<<dim3(M_ / 256, C_ / 128), 256, 0, stream>>>(y, Wpt, b_proj, C_, C_, nullptr, out);
}

// Round 6
// 212.968 us; speedup vs baseline: 1.0070x; 1.0070x over previous
//
#include <hip/hip_runtime.h>
#include <hip/hip_bf16.h>

#define B_ 4
#define T_ 2048
#define C_ 1024
#define H_ 16
#define HD_ 64
#define M_ (B_*T_)        // 8192 rows
#define N3_ (3*C_)        // 3072
#define QKVSZ (B_*H_*T_*HD_)  // 8388608 elems per tensor
#define QSCALE 0.1803368801f  // 0.125 * log2(e)

typedef unsigned short u16;
typedef unsigned int u32;
typedef __attribute__((ext_vector_type(8))) __bf16 bf16x8;
typedef __attribute__((ext_vector_type(4))) float f32x4;
typedef __attribute__((ext_vector_type(16))) float f32x16;
typedef __attribute__((ext_vector_type(2))) int i32x2;
typedef __attribute__((ext_vector_type(4))) u32 u32x4;
typedef const __attribute__((address_space(1))) void* gptr_t;
typedef __attribute__((address_space(3))) void* sptr_t;

__device__ __forceinline__ u16 f2b(float f) {
  __hip_bfloat16 h = __float2bfloat16(f);
  return __builtin_bit_cast(u16, h);
}

// v_cvt_pk_bf16_f32: lo -> bits[15:0], hi -> bits[31:16]
__device__ __forceinline__ u32 cvtpk(float lo, float hi) {
  u32 r;
  asm volatile("v_cvt_pk_bf16_f32 %0, %1, %2" : "=v"(r) : "v"(lo), "v"(hi));
  return r;
}

// ---------------- fp32 -> bf16 convert (vectorized) ----------------
__global__ __launch_bounds__(256) void cvt_kernel(const float* __restrict__ src,
                                                  u16* __restrict__ dst, int n4) {
  int i = blockIdx.x * blockDim.x + threadIdx.x;
  int stride = gridDim.x * blockDim.x;
  for (; i < n4; i += stride) {
    float4 f = ((const float4*)src)[i];
    ushort4 o;
    o.x = f2b(f.x); o.y = f2b(f.y); o.z = f2b(f.z); o.w = f2b(f.w);
    ((ushort4*)dst)[i] = o;
  }
}

// ---------------- transpose + convert: src[K][N] fp32 -> dst[N][K] bf16 ----------------
__global__ __launch_bounds__(256) void tr_cvt(const float* __restrict__ src,
                                              u16* __restrict__ dst, int K, int N) {
  __shared__ u16 tile[64][72];   // +8 pad
  int k0 = blockIdx.x * 64, n0 = blockIdx.y * 64;
  #pragma unroll
  for (int t = 0; t < 16; ++t) {
    int idx = threadIdx.x + t * 256;
    int r = idx >> 6, c = idx & 63;
    tile[r][c] = f2b(src[(size_t)(k0 + r) * N + n0 + c]);
  }
  __syncthreads();
  #pragma unroll
  for (int t = 0; t < 16; ++t) {
    int idx = threadIdx.x + t * 256;
    int r = idx >> 6, c = idx & 63;       // r = local n, c = local k
    dst[(size_t)(n0 + r) * K + k0 + c] = tile[c][r];
  }
}

// ---------------- GEMM: C[M][N] = A[M][K] * Bt[N][K]^T + bias ----------------
// BM=256 x BN=128, BK=32, 4 waves each owning 128x64 (acc 8x4).
// 3-deep LDS pipeline with COUNTED vmcnt (T4): stage(t+2) issued at top of
// iter t; end-of-iter waits vmcnt(6) (only tile t+1's loads) + raw s_barrier
// -> tile t+2's 6 loads stay in flight across the barrier (never drain to 0).
// Granule-XOR swizzle via pre-swizzled global source + swizzled ds_read.
// EPI 0: scatter to q (scaled) / k / v^T.  EPI 1: fp32 out [M][N].
template <int EPI>
__global__ __launch_bounds__(256, 2) void gemm_bt(const u16* __restrict__ A,
                                                  const u16* __restrict__ Bt,
                                                  const float* __restrict__ bias,
                                                  int K, int N,
                                                  u16* __restrict__ out_qkv,
                                                  float* __restrict__ out_f) {
  __shared__ __align__(16) u16 As[3][256 * 32];
  __shared__ __align__(16) u16 Bs[3][128 * 32];
  const int tid = threadIdx.x;
  const int wave = tid >> 6, lane = tid & 63;
  const int lr = lane & 15, lk = lane >> 4;

  const int m0 = blockIdx.x * 256, n0 = blockIdx.y * 128;
  const int wr = (wave >> 1) * 128, wc = (wave & 1) * 64;

  f32x4 acc[8][4] = {};

  auto stage = [&](int buf, int it) {
    const int kt = it * 32;
    #pragma unroll
    for (int i = 0; i < 4; ++i) {                // A: 1024 chunks / 256 thr
      int ch = i * 256 + wave * 64 + lane;
      int row = ch >> 2;
      int gsrc = (ch & 3) ^ ((row >> 1) & 3);
      __builtin_amdgcn_global_load_lds((gptr_t)(A + (size_t)(m0 + row) * K + kt + gsrc * 8),
                                       (sptr_t)(&As[buf][ch * 8]), 16, 0, 0);
    }
    #pragma unroll
    for (int i = 0; i < 2; ++i) {                // B: 512 chunks / 256 thr
      int ch = i * 256 + wave * 64 + lane;
      int row = ch >> 2;
      int gsrc = (ch & 3) ^ ((row >> 1) & 3);
      __builtin_amdgcn_global_load_lds((gptr_t)(Bt + (size_t)(n0 + row) * K + kt + gsrc * 8),
                                       (sptr_t)(&Bs[buf][ch * 8]), 16, 0, 0);
    }
  };

  const int KI = K / 32;                         // 32 iters (K=1024)
  stage(0, 0);
  stage(1, 1);
  asm volatile("s_waitcnt vmcnt(6)" ::: "memory");   // tile 0 complete
  __builtin_amdgcn_s_barrier();

  for (int it = 0; it < KI; ++it) {
    const int cur = it % 3;
    const bool pre = (it + 2 < KI);
    if (pre) stage((it + 2) % 3, it + 2);        // overlaps 2 full iterations

    bf16x8 af[8], bfr[4];
    #pragma unroll
    for (int mi = 0; mi < 8; ++mi) {
      int r = wr + mi * 16 + lr;
      af[mi] = *(const bf16x8*)(&As[cur][r * 32 + ((lk ^ ((r >> 1) & 3)) << 3)]);
    }
    #pragma unroll
    for (int ni = 0; ni < 4; ++ni) {
      int r = wc + ni * 16 + lr;
      bfr[ni] = *(const bf16x8*)(&Bs[cur][r * 32 + ((lk ^ ((r >> 1) & 3)) << 3)]);
    }
    #pragma unroll
    for (int mi = 0; mi < 8; ++mi)
      #pragma unroll
      for (int ni = 0; ni < 4; ++ni)
        acc[mi][ni] = __builtin_amdgcn_mfma_f32_16x16x32_bf16(af[mi], bfr[ni], acc[mi][ni], 0, 0, 0);

    if (pre) asm volatile("s_waitcnt vmcnt(6)" ::: "memory");  // t+1 done, t+2 in flight
    else     asm volatile("s_waitcnt vmcnt(0)" ::: "memory");  // pipeline drain (last 2 iters)
    __builtin_amdgcn_s_barrier();
  }

  if (EPI == 0) {
    const int sel = (n0 >> 10);                   // whole block same q/k/v segment
    #pragma unroll
    for (int mi = 0; mi < 8; ++mi) {
      #pragma unroll
      for (int ni = 0; ni < 4; ++ni) {
        int m = m0 + wr + mi * 16 + lk * 4;       // +j
        int n = n0 + wc + ni * 16 + lr;
        int rem = n & 1023, h = rem >> 6, d = rem & 63;
        int b = m >> 11, t = m & 2047;
        if (sel == 2) {                           // v^T: t contiguous -> ushort4
          ushort4 st;
          #pragma unroll
          for (int j = 0; j < 4; ++j)
            ((u16*)&st)[j] = f2b(acc[mi][ni][j] + bias[n]);
          *(ushort4*)(out_qkv + 2 * (size_t)QKVSZ +
                      (((size_t)(b * H_ + h) * HD_ + d) * T_ + t)) = st;
        } else {
          #pragma unroll
          for (int j = 0; j < 4; ++j) {
            float val = acc[mi][ni][j] + bias[n];
            if (sel == 0) val *= QSCALE;
            out_qkv[(size_t)sel * QKVSZ +
                    (((size_t)(b * H_ + h) * T_ + (t + j)) * HD_ + d)] = f2b(val);
          }
        }
      }
    }
  } else {
    #pragma unroll
    for (int mi = 0; mi < 8; ++mi)
      #pragma unroll
      for (int ni = 0; ni < 4; ++ni)
        #pragma unroll
        for (int j = 0; j < 4; ++j) {
          int m = m0 + wr + mi * 16 + lk * 4 + j;
          int n = n0 + wc + ni * 16 + lr;
          out_f[(size_t)m * C_ + n] = acc[mi][ni][j] + bias[n];
        }
  }
}

// ---------------- causal flash attention ----------------
// 128 threads = 2 waves; q-tile 64 (wave w owns q-rows [BQ+32w, BQ+32w+32)).
// grid (bh=64, 32 q-tiles) = 2048 blocks, heavy-first. 32x32x16 MFMAs,
// swapped S^T = mfma(K,Q). Softmax per-lane + 1 shfl_xor(32). P in registers
// via cvt_pk + permlane32_swap. O^T = mfma(Vt, P). K/V dbuf + prefetch.
__global__ __launch_bounds__(128, 2) void attn_k(const u16* __restrict__ q,
                                                 const u16* __restrict__ k,
                                                 const u16* __restrict__ vt,
                                                 u16* __restrict__ y) {
  __shared__ __align__(16) u16 Ks[2][64 * 64];
  __shared__ __align__(16) u16 Vs[2][64 * 64];
  const int tid = threadIdx.x;
  const int wave = tid >> 6, lane = tid & 63;
  const int hi = lane >> 5, lq = lane & 31;
  const int qtb = gridDim.y - 1 - blockIdx.y;    // 31..0, heavy first
  const int bh = blockIdx.x;                     // fastest dim -> XCD spread
  const size_t koff = (size_t)bh * T_ * HD_;     // q,k: [bh][t][d]
  const size_t voff = (size_t)bh * HD_ * T_;     // vt:  [bh][d][t]
  const int qrow = qtb * 64 + 32 * wave + lq;    // this lane's q row (global)

  // Q B-frags (pre-scaled by 0.125*log2e): qf[c] = Q[qrow][16c+8hi .. +8]
  bf16x8 qf[4];
  #pragma unroll
  for (int c = 0; c < 4; ++c)
    qf[c] = *(const bf16x8*)(q + koff + (size_t)qrow * HD_ + 16 * c + 8 * hi);

  f32x16 o[2] = {};                              // [dh]: O^T rows 32dh..
  float mrun = -1e30f, lsum = 0.f;

  auto stage = [&](int buf, int kt) {
    const u16* kb = k + koff + (size_t)kt * 64 * HD_;
    const u16* vb = vt + voff + (size_t)kt * 64;
    #pragma unroll
    for (int j = 0; j < 4; ++j) {
      int cb = j * 128 + wave * 64;              // wave-uniform chunk base
      int ch = cb + lane;
      int row = ch >> 3, gg = ch & 7;
      int src = gg ^ (row & 7);                  // pre-swizzled global source
      __builtin_amdgcn_global_load_lds((gptr_t)(kb + row * HD_ + src * 8),
                                       (sptr_t)(&Ks[buf][cb * 8]), 16, 0, 0);
      __builtin_amdgcn_global_load_lds((gptr_t)(vb + (size_t)row * T_ + src * 8),
                                       (sptr_t)(&Vs[buf][cb * 8]), 16, 0, 0);
    }
  };

  const int nt = qtb + 1;
  stage(0, 0);
  __syncthreads();

  for (int kt = 0; kt < nt; ++kt) {
    const int cur = kt & 1;
    if (kt + 1 < nt) stage(cur ^ 1, kt + 1);
    const bool dia = (kt == qtb);
    const bool skip1 = dia && (wave == 0);       // kh=1 fully masked (wave-uniform)
    const u16* Kb = &Ks[cur][0];
    const u16* Vb = &Vs[cur][0];

    // ---- S^T = K Q^T ----
    f32x16 s[2] = {};
    #pragma unroll
    for (int c = 0; c < 4; ++c) {
      #pragma unroll
      for (int kh = 0; kh < 2; ++kh) {
        if (kh == 1 && skip1) continue;
        int row = 32 * kh + lq;
        bf16x8 kf = *(const bf16x8*)(Kb + row * 64 + (((2 * c + hi) ^ (row & 7)) << 3));
        s[kh] = __builtin_amdgcn_mfma_f32_32x32x16_bf16(kf, qf[c], s[kh], 0, 0, 0);
      }
    }

    if (dia) {
      // wave 0: kh0 diagonal-masked; wave 1: kh0 fully visible, kh1 diagonal-masked
      #pragma unroll
      for (int rr = 0; rr < 16; ++rr) {
        int kg = 64 * kt + 4 * hi + (rr & 3) + 8 * (rr >> 2);
        if (wave == 0) { if (kg > qrow) s[0][rr] = -1e30f; }
        else           { if (kg + 32 > qrow) s[1][rr] = -1e30f; }
      }
    }

    // ---- online softmax (lane and lane^32 share a q-row) ----
    float tm = -1e30f;
    #pragma unroll
    for (int kh = 0; kh < 2; ++kh) {
      if (kh == 1 && skip1) continue;
      #pragma unroll
      for (int rr = 0; rr < 16; ++rr) tm = fmaxf(tm, s[kh][rr]);
    }
    tm = fmaxf(tm, __shfl_xor(tm, 32));
    if (__any(tm > mrun + 8.f)) {                // defer-max (T13)
      float mn = fmaxf(mrun, tm);
      float al = exp2f(mrun - mn);
      lsum *= al;
      o[0] *= al;
      o[1] *= al;
      mrun = mn;
    }
    float rs = 0.f;
    #pragma unroll
    for (int kh = 0; kh < 2; ++kh) {
      if (kh == 1 && skip1) continue;
      #pragma unroll
      for (int rr = 0; rr < 16; ++rr) {
        float p = exp2f(s[kh][rr] - mrun);
        s[kh][rr] = p;
        rs += p;
      }
    }
    rs += __shfl_xor(rs, 32);
    lsum += rs;

    // ---- PV: O^T[d][q] += Vt P (P assembled in-register) ----
    #pragma unroll
    for (int kh = 0; kh < 2; ++kh) {
      if (kh == 1 && skip1) continue;
      bf16x8 pf[2];
      #pragma unroll
      for (int ct = 0; ct < 2; ++ct) {
        u32 A0 = cvtpk(s[kh][8 * ct + 0], s[kh][8 * ct + 1]);
        u32 A1 = cvtpk(s[kh][8 * ct + 2], s[kh][8 * ct + 3]);
        u32 B0 = cvtpk(s[kh][8 * ct + 4], s[kh][8 * ct + 5]);
        u32 B1 = cvtpk(s[kh][8 * ct + 6], s[kh][8 * ct + 7]);
        i32x2 r0 = __builtin_amdgcn_permlane32_swap((int)A0, (int)B0, false, false);
        i32x2 r1 = __builtin_amdgcn_permlane32_swap((int)A1, (int)B1, false, false);
        u32x4 w = {(u32)r0[0], (u32)r1[0], (u32)r0[1], (u32)r1[1]};
        pf[ct] = __builtin_bit_cast(bf16x8, w);
      }
      #pragma unroll
      for (int ct = 0; ct < 2; ++ct)
        #pragma unroll
        for (int dh = 0; dh < 2; ++dh) {
          int row = 32 * dh + lq;
          bf16x8 vf = *(const bf16x8*)(Vb + row * 64 + (((4 * kh + 2 * ct + hi) ^ (row & 7)) << 3));
          o[dh] = __builtin_amdgcn_mfma_f32_32x32x16_bf16(vf, pf[ct], o[dh], 0, 0, 0);
        }
    }
    __syncthreads();
  }

  // ---- epilogue: y[b,t,h*64+d] = O^T[d][q] / l ----
  const int b = bh >> 4, h = bh & 15;
  float li = 1.0f / lsum;
  u16* yrow = y + (size_t)(b * T_ + qrow) * C_ + h * 64;
  #pragma unroll
  for (int dh = 0; dh < 2; ++dh)
    #pragma unroll
    for (int u = 0; u < 4; ++u) {
      ushort4 st;
      st.x = f2b(o[dh][4 * u + 0] * li);
      st.y = f2b(o[dh][4 * u + 1] * li);
      st.z = f2b(o[dh][4 * u + 2] * li);
      st.w = f2b(o[dh][4 * u + 3] * li);
      *(ushort4*)(yrow + 32 * dh + 8 * u + 4 * hi) = st;
    }
}

extern "C" void kernel_launch(void* const* d_in, const int* in_sizes, int n_in,
                              void* d_out, int out_size, void* d_ws, size_t ws_size,
                              hipStream_t stream) {
  const float* x      = (const float*)d_in[0];
  const float* W_attn = (const float*)d_in[1];
  const float* b_attn = (const float*)d_in[2];
  const float* W_proj = (const float*)d_in[3];
  const float* b_proj = (const float*)d_in[4];
  float* out = (float*)d_out;

  u16* ws = (u16*)d_ws;
  u16* xb  = ws;
  u16* Wat = xb + (size_t)M_ * C_;
  u16* Wpt = Wat + (size_t)N3_ * C_;
  u16* qkv = Wpt + (size_t)C_ * C_;
  u16* y   = qkv + (size_t)3 * QKVSZ;

  cvt_kernel<<<2048, 256, 0, stream>>>(x, xb, M_ * C_ / 4);
  tr_cvt<<<dim3(C_ / 64, N3_ / 64), 256, 0, stream>>>(W_attn, Wat, C_, N3_);
  tr_cvt<<<dim3(C_ / 64, C_ / 64), 256, 0, stream>>>(W_proj, Wpt, C_, C_);
  gemm_bt<0><<<dim3(M_ / 256, N3_ / 128), 256, 0, stream>>>(xb, Wat, b_attn, C_, N3_, qkv, nullptr);
  attn_k<<<dim3(B_ * H_, T_ / 64), 128, 0, stream>>>(qkv, qkv + QKVSZ, qkv + 2 * QKVSZ, y);
  gemm_bt<1><<<dim3(M_ / 256, C_ / 128), 256, 0, stream>>>(y, Wpt, b_proj, C_, C_, nullptr, out);
}

// Round 8
// 198.215 us; speedup vs baseline: 1.0819x; 1.0744x over previous
//
#include <hip/hip_runtime.h>
#include <hip/hip_bf16.h>

#define B_ 4
#define T_ 2048
#define C_ 1024
#define H_ 16
#define HD_ 64
#define M_ (B_*T_)        // 8192 rows
#define N3_ (3*C_)        // 3072
#define QKVSZ (B_*H_*T_*HD_)  // 8388608 elems per tensor
#define QSCALE 0.1803368801f  // 0.125 * log2(e)

typedef unsigned short u16;
typedef unsigned int u32;
typedef __attribute__((ext_vector_type(8))) __bf16 bf16x8;
typedef __attribute__((ext_vector_type(4))) float f32x4;
typedef __attribute__((ext_vector_type(16))) float f32x16;
typedef __attribute__((ext_vector_type(2))) int i32x2;
typedef __attribute__((ext_vector_type(4))) u32 u32x4;
typedef const __attribute__((address_space(1))) void* gptr_t;
typedef __attribute__((address_space(3))) void* sptr_t;

__device__ __forceinline__ u16 f2b(float f) {
  __hip_bfloat16 h = __float2bfloat16(f);
  return __builtin_bit_cast(u16, h);
}

// v_cvt_pk_bf16_f32: lo -> bits[15:0], hi -> bits[31:16]
__device__ __forceinline__ u32 cvtpk(float lo, float hi) {
  u32 r;
  asm volatile("v_cvt_pk_bf16_f32 %0, %1, %2" : "=v"(r) : "v"(lo), "v"(hi));
  return r;
}

// ---------------- fp32 -> bf16 convert (vectorized) ----------------
__global__ __launch_bounds__(256) void cvt_kernel(const float* __restrict__ src,
                                                  u16* __restrict__ dst, int n4) {
  int i = blockIdx.x * blockDim.x + threadIdx.x;
  int stride = gridDim.x * blockDim.x;
  for (; i < n4; i += stride) {
    float4 f = ((const float4*)src)[i];
    ushort4 o;
    o.x = f2b(f.x); o.y = f2b(f.y); o.z = f2b(f.z); o.w = f2b(f.w);
    ((ushort4*)dst)[i] = o;
  }
}

// ---------------- transpose + convert: src[K][N] fp32 -> dst[N][K] bf16 ----------------
__global__ __launch_bounds__(256) void tr_cvt(const float* __restrict__ src,
                                              u16* __restrict__ dst, int K, int N) {
  __shared__ u16 tile[64][72];   // +8 pad
  int k0 = blockIdx.x * 64, n0 = blockIdx.y * 64;
  #pragma unroll
  for (int t = 0; t < 16; ++t) {
    int idx = threadIdx.x + t * 256;
    int r = idx >> 6, c = idx & 63;
    tile[r][c] = f2b(src[(size_t)(k0 + r) * N + n0 + c]);
  }
  __syncthreads();
  #pragma unroll
  for (int t = 0; t < 16; ++t) {
    int idx = threadIdx.x + t * 256;
    int r = idx >> 6, c = idx & 63;       // r = local n, c = local k
    dst[(size_t)(n0 + r) * K + k0 + c] = tile[c][r];
  }
}

// ---------------- GEMM: C[M][N] = A[M][K] * Bt[N][K]^T + bias ----------------
// BM=256 x BN=128, BK=32, 4 waves each owning 128x64 (acc 8x4).
// 3-deep LDS pipeline with COUNTED vmcnt (T4): stage(t+2) issued at top of
// iter t; end-of-iter waits vmcnt(6) (only tile t+1's loads) + raw s_barrier
// -> tile t+2's 6 loads stay in flight across the barrier (never drain to 0).
// Granule-XOR swizzle via pre-swizzled global source + swizzled ds_read.
// EPI 0: scatter to q (scaled) / k / v^T.  EPI 1: fp32 out [M][N].
template <int EPI>
__global__ __launch_bounds__(256, 2) void gemm_bt(const u16* __restrict__ A,
                                                  const u16* __restrict__ Bt,
                                                  const float* __restrict__ bias,
                                                  int K, int N,
                                                  u16* __restrict__ out_qkv,
                                                  float* __restrict__ out_f) {
  __shared__ __align__(16) u16 As[3][256 * 32];
  __shared__ __align__(16) u16 Bs[3][128 * 32];
  const int tid = threadIdx.x;
  const int wave = tid >> 6, lane = tid & 63;
  const int lr = lane & 15, lk = lane >> 4;

  const int m0 = blockIdx.x * 256, n0 = blockIdx.y * 128;
  const int wr = (wave >> 1) * 128, wc = (wave & 1) * 64;

  f32x4 acc[8][4] = {};

  auto stage = [&](int buf, int it) {
    const int kt = it * 32;
    #pragma unroll
    for (int i = 0; i < 4; ++i) {                // A: 1024 chunks / 256 thr
      int ch = i * 256 + wave * 64 + lane;
      int row = ch >> 2;
      int gsrc = (ch & 3) ^ ((row >> 1) & 3);
      __builtin_amdgcn_global_load_lds((gptr_t)(A + (size_t)(m0 + row) * K + kt + gsrc * 8),
                                       (sptr_t)(&As[buf][ch * 8]), 16, 0, 0);
    }
    #pragma unroll
    for (int i = 0; i < 2; ++i) {                // B: 512 chunks / 256 thr
      int ch = i * 256 + wave * 64 + lane;
      int row = ch >> 2;
      int gsrc = (ch & 3) ^ ((row >> 1) & 3);
      __builtin_amdgcn_global_load_lds((gptr_t)(Bt + (size_t)(n0 + row) * K + kt + gsrc * 8),
                                       (sptr_t)(&Bs[buf][ch * 8]), 16, 0, 0);
    }
  };

  const int KI = K / 32;                         // 32 iters (K=1024)
  stage(0, 0);
  stage(1, 1);
  asm volatile("s_waitcnt vmcnt(6)" ::: "memory");   // tile 0 complete
  __builtin_amdgcn_s_barrier();

  for (int it = 0; it < KI; ++it) {
    const int cur = it % 3;
    const bool pre = (it + 2 < KI);
    if (pre) stage((it + 2) % 3, it + 2);        // overlaps 2 full iterations

    bf16x8 af[8], bfr[4];
    #pragma unroll
    for (int mi = 0; mi < 8; ++mi) {
      int r = wr + mi * 16 + lr;
      af[mi] = *(const bf16x8*)(&As[cur][r * 32 + ((lk ^ ((r >> 1) & 3)) << 3)]);
    }
    #pragma unroll
    for (int ni = 0; ni < 4; ++ni) {
      int r = wc + ni * 16 + lr;
      bfr[ni] = *(const bf16x8*)(&Bs[cur][r * 32 + ((lk ^ ((r >> 1) & 3)) << 3)]);
    }
    #pragma unroll
    for (int mi = 0; mi < 8; ++mi)
      #pragma unroll
      for (int ni = 0; ni < 4; ++ni)
        acc[mi][ni] = __builtin_amdgcn_mfma_f32_16x16x32_bf16(af[mi], bfr[ni], acc[mi][ni], 0, 0, 0);

    if (pre) asm volatile("s_waitcnt vmcnt(6)" ::: "memory");  // t+1 done, t+2 in flight
    else     asm volatile("s_waitcnt vmcnt(0)" ::: "memory");  // pipeline drain (last 2 iters)
    __builtin_amdgcn_s_barrier();
  }

  if (EPI == 0) {
    const int sel = (n0 >> 10);                   // whole block same q/k/v segment
    #pragma unroll
    for (int mi = 0; mi < 8; ++mi) {
      #pragma unroll
      for (int ni = 0; ni < 4; ++ni) {
        int m = m0 + wr + mi * 16 + lk * 4;       // +j
        int n = n0 + wc + ni * 16 + lr;
        int rem = n & 1023, h = rem >> 6, d = rem & 63;
        int b = m >> 11, t = m & 2047;
        if (sel == 2) {                           // v^T: t contiguous -> ushort4
          ushort4 st;
          #pragma unroll
          for (int j = 0; j < 4; ++j)
            ((u16*)&st)[j] = f2b(acc[mi][ni][j] + bias[n]);
          *(ushort4*)(out_qkv + 2 * (size_t)QKVSZ +
                      (((size_t)(b * H_ + h) * HD_ + d) * T_ + t)) = st;
        } else {
          #pragma unroll
          for (int j = 0; j < 4; ++j) {
            float val = acc[mi][ni][j] + bias[n];
            if (sel == 0) val *= QSCALE;
            out_qkv[(size_t)sel * QKVSZ +
                    (((size_t)(b * H_ + h) * T_ + (t + j)) * HD_ + d)] = f2b(val);
          }
        }
      }
    }
  } else {
    #pragma unroll
    for (int mi = 0; mi < 8; ++mi)
      #pragma unroll
      for (int ni = 0; ni < 4; ++ni)
        #pragma unroll
        for (int j = 0; j < 4; ++j) {
          int m = m0 + wr + mi * 16 + lk * 4 + j;
          int n = n0 + wc + ni * 16 + lr;
          out_f[(size_t)m * C_ + n] = acc[mi][ni][j] + bias[n];
        }
  }
}

// ---------------- causal flash attention ----------------
// 128 threads = 2 waves; q-tile 64 (wave w owns q-rows [BQ+32w, BQ+32w+32)).
// grid (bh=64, 32 q-tiles) = 2048 blocks, heavy-first. 32x32x16 MFMAs,
// swapped S^T = mfma(K,Q). Softmax per-lane: raw v_exp_f32 (builtin exp2),
// cross-half reduce via __shfl_xor(32) (permlane32_swap(x,x) aliases the
// in-place swap when RA coalesces equal operands -> r[0]==r[1]; NOT usable
// for self-reduce). P in registers via cvt_pk + permlane32_swap (distinct
// operands -> safe). O^T = mfma(Vt, P). K/V dbuf + prefetch.
__global__ __launch_bounds__(128, 2) void attn_k(const u16* __restrict__ q,
                                                 const u16* __restrict__ k,
                                                 const u16* __restrict__ vt,
                                                 u16* __restrict__ y) {
  __shared__ __align__(16) u16 Ks[2][64 * 64];
  __shared__ __align__(16) u16 Vs[2][64 * 64];
  const int tid = threadIdx.x;
  const int wave = tid >> 6, lane = tid & 63;
  const int hi = lane >> 5, lq = lane & 31;
  const int qtb = gridDim.y - 1 - blockIdx.y;    // 31..0, heavy first
  const int bh = blockIdx.x;                     // fastest dim -> XCD spread
  const size_t koff = (size_t)bh * T_ * HD_;     // q,k: [bh][t][d]
  const size_t voff = (size_t)bh * HD_ * T_;     // vt:  [bh][d][t]
  const int qrow = qtb * 64 + 32 * wave + lq;    // this lane's q row (global)

  // Q B-frags (pre-scaled by 0.125*log2e): qf[c] = Q[qrow][16c+8hi .. +8]
  bf16x8 qf[4];
  #pragma unroll
  for (int c = 0; c < 4; ++c)
    qf[c] = *(const bf16x8*)(q + koff + (size_t)qrow * HD_ + 16 * c + 8 * hi);

  f32x16 o[2] = {};                              // [dh]: O^T rows 32dh..
  float mrun = -1e30f, lsum = 0.f;

  auto stage = [&](int buf, int kt) {
    const u16* kb = k + koff + (size_t)kt * 64 * HD_;
    const u16* vb = vt + voff + (size_t)kt * 64;
    #pragma unroll
    for (int j = 0; j < 4; ++j) {
      int cb = j * 128 + wave * 64;              // wave-uniform chunk base
      int ch = cb + lane;
      int row = ch >> 3, gg = ch & 7;
      int src = gg ^ (row & 7);                  // pre-swizzled global source
      __builtin_amdgcn_global_load_lds((gptr_t)(kb + row * HD_ + src * 8),
                                       (sptr_t)(&Ks[buf][cb * 8]), 16, 0, 0);
      __builtin_amdgcn_global_load_lds((gptr_t)(vb + (size_t)row * T_ + src * 8),
                                       (sptr_t)(&Vs[buf][cb * 8]), 16, 0, 0);
    }
  };

  const int nt = qtb + 1;
  stage(0, 0);
  __syncthreads();

  for (int kt = 0; kt < nt; ++kt) {
    const int cur = kt & 1;
    if (kt + 1 < nt) stage(cur ^ 1, kt + 1);
    const bool dia = (kt == qtb);
    const bool skip1 = dia && (wave == 0);       // kh=1 fully masked (wave-uniform)
    const u16* Kb = &Ks[cur][0];
    const u16* Vb = &Vs[cur][0];

    // ---- S^T = K Q^T ----
    f32x16 s[2] = {};
    #pragma unroll
    for (int c = 0; c < 4; ++c) {
      #pragma unroll
      for (int kh = 0; kh < 2; ++kh) {
        if (kh == 1 && skip1) continue;
        int row = 32 * kh + lq;
        bf16x8 kf = *(const bf16x8*)(Kb + row * 64 + (((2 * c + hi) ^ (row & 7)) << 3));
        s[kh] = __builtin_amdgcn_mfma_f32_32x32x16_bf16(kf, qf[c], s[kh], 0, 0, 0);
      }
    }

    if (dia) {
      // wave 0: kh0 diagonal-masked; wave 1: kh0 fully visible, kh1 diagonal-masked
      #pragma unroll
      for (int rr = 0; rr < 16; ++rr) {
        int kg = 64 * kt + 4 * hi + (rr & 3) + 8 * (rr >> 2);
        if (wave == 0) { if (kg > qrow) s[0][rr] = -1e30f; }
        else           { if (kg + 32 > qrow) s[1][rr] = -1e30f; }
      }
    }

    // ---- online softmax (lane and lane^32 share a q-row) ----
    // max tree in v_max3-fusible groups, short dep chains
    float g0, g1, g2, g3;
    {
      const f32x16& a = s[0];
      g0 = fmaxf(fmaxf(a[0], a[1]),   fmaxf(a[2], a[3]));
      g1 = fmaxf(fmaxf(a[4], a[5]),   fmaxf(a[6], a[7]));
      g2 = fmaxf(fmaxf(a[8], a[9]),   fmaxf(a[10], a[11]));
      g3 = fmaxf(fmaxf(a[12], a[13]), fmaxf(a[14], a[15]));
    }
    if (!skip1) {
      const f32x16& a = s[1];
      g0 = fmaxf(g0, fmaxf(fmaxf(a[0], a[1]),   fmaxf(a[2], a[3])));
      g1 = fmaxf(g1, fmaxf(fmaxf(a[4], a[5]),   fmaxf(a[6], a[7])));
      g2 = fmaxf(g2, fmaxf(fmaxf(a[8], a[9]),   fmaxf(a[10], a[11])));
      g3 = fmaxf(g3, fmaxf(fmaxf(a[12], a[13]), fmaxf(a[14], a[15])));
    }
    float tm = fmaxf(fmaxf(g0, g1), fmaxf(g2, g3));
    tm = fmaxf(tm, __shfl_xor(tm, 32));
    if (__any(tm > mrun + 8.f)) {                // defer-max (T13)
      float mn = fmaxf(mrun, tm);
      float al = __builtin_amdgcn_exp2f(mrun - mn);
      lsum *= al;
      o[0] *= al;
      o[1] *= al;
      mrun = mn;
    }
    float rs = 0.f;
    #pragma unroll
    for (int kh = 0; kh < 2; ++kh) {
      if (kh == 1 && skip1) continue;
      #pragma unroll
      for (int rr = 0; rr < 16; ++rr) {
        float p = __builtin_amdgcn_exp2f(s[kh][rr] - mrun);
        s[kh][rr] = p;
        rs += p;
      }
    }
    rs += __shfl_xor(rs, 32);
    lsum += rs;

    // ---- PV: O^T[d][q] += Vt P (P assembled in-register) ----
    #pragma unroll
    for (int kh = 0; kh < 2; ++kh) {
      if (kh == 1 && skip1) continue;
      bf16x8 pf[2];
      #pragma unroll
      for (int ct = 0; ct < 2; ++ct) {
        u32 A0 = cvtpk(s[kh][8 * ct + 0], s[kh][8 * ct + 1]);
        u32 A1 = cvtpk(s[kh][8 * ct + 2], s[kh][8 * ct + 3]);
        u32 B0 = cvtpk(s[kh][8 * ct + 4], s[kh][8 * ct + 5]);
        u32 B1 = cvtpk(s[kh][8 * ct + 6], s[kh][8 * ct + 7]);
        i32x2 r0 = __builtin_amdgcn_permlane32_swap((int)A0, (int)B0, false, false);
        i32x2 r1 = __builtin_amdgcn_permlane32_swap((int)A1, (int)B1, false, false);
        u32x4 w = {(u32)r0[0], (u32)r1[0], (u32)r0[1], (u32)r1[1]};
        pf[ct] = __builtin_bit_cast(bf16x8, w);
      }
      #pragma unroll
      for (int ct = 0; ct < 2; ++ct)
        #pragma unroll
        for (int dh = 0; dh < 2; ++dh) {
          int row = 32 * dh + lq;
          bf16x8 vf = *(const bf16x8*)(Vb + row * 64 + (((4 * kh + 2 * ct + hi) ^ (row & 7)) << 3));
          o[dh] = __builtin_amdgcn_mfma_f32_32x32x16_bf16(vf, pf[ct], o[dh], 0, 0, 0);
        }
    }
    __syncthreads();
  }

  // ---- epilogue: y[b,t,h*64+d] = O^T[d][q] / l ----
  const int b = bh >> 4, h = bh & 15;
  float li = 1.0f / lsum;
  u16* yrow = y + (size_t)(b * T_ + qrow) * C_ + h * 64;
  #pragma unroll
  for (int dh = 0; dh < 2; ++dh)
    #pragma unroll
    for (int u = 0; u < 4; ++u) {
      ushort4 st;
      st.x = f2b(o[dh][4 * u + 0] * li);
      st.y = f2b(o[dh][4 * u + 1] * li);
      st.z = f2b(o[dh][4 * u + 2] * li);
      st.w = f2b(o[dh][4 * u + 3] * li);
      *(ushort4*)(yrow + 32 * dh + 8 * u + 4 * hi) = st;
    }
}

extern "C" void kernel_launch(void* const* d_in, const int* in_sizes, int n_in,
                              void* d_out, int out_size, void* d_ws, size_t ws_size,
                              hipStream_t stream) {
  const float* x      = (const float*)d_in[0];
  const float* W_attn = (const float*)d_in[1];
  const float* b_attn = (const float*)d_in[2];
  const float* W_proj = (const float*)d_in[3];
  const float* b_proj = (const float*)d_in[4];
  float* out = (float*)d_out;

  u16* ws = (u16*)d_ws;
  u16* xb  = ws;
  u16* Wat = xb + (size_t)M_ * C_;
  u16* Wpt = Wat + (size_t)N3_ * C_;
  u16* qkv = Wpt + (size_t)C_ * C_;
  u16* y   = qkv + (size_t)3 * QKVSZ;

  cvt_kernel<<<2048, 256, 0, stream>>>(x, xb, M_ * C_ / 4);
  tr_cvt<<<dim3(C_ / 64, N3_ / 64), 256, 0, stream>>>(W_attn, Wat, C_, N3_);
  tr_cvt<<<dim3(C_ / 64, C_ / 64), 256, 0, stream>>>(W_proj, Wpt, C_, C_);
  gemm_bt<0><<<dim3(M_ / 256, N3_ / 128), 256, 0, stream>>>(xb, Wat, b_attn, C_, N3_, qkv, nullptr);
  attn_k<<<dim3(B_ * H_, T_ / 64), 128, 0, stream>>>(qkv, qkv + QKVSZ, qkv + 2 * QKVSZ, y);
  gemm_bt<1><<<dim3(M_ / 256, C_ / 128), 256, 0, stream>>>(y, Wpt, b_proj, C_, C_, nullptr, out);
}

// Round 9
// 182.320 us; speedup vs baseline: 1.1763x; 1.0872x over previous
//
#include <hip/hip_runtime.h>
#include <hip/hip_bf16.h>

#define B_ 4
#define T_ 2048
#define C_ 1024
#define H_ 16
#define HD_ 64
#define M_ (B_*T_)        // 8192 rows
#define N3_ (3*C_)        // 3072
#define QKVSZ (B_*H_*T_*HD_)  // 8388608 elems per tensor
#define QSCALE 0.1803368801f  // 0.125 * log2(e)

typedef unsigned short u16;
typedef unsigned int u32;
typedef __attribute__((ext_vector_type(8))) __bf16 bf16x8;
typedef __attribute__((ext_vector_type(4))) float f32x4;
typedef __attribute__((ext_vector_type(16))) float f32x16;
typedef __attribute__((ext_vector_type(2))) int i32x2;
typedef __attribute__((ext_vector_type(4))) u32 u32x4;
typedef const __attribute__((address_space(1))) void* gptr_t;
typedef __attribute__((address_space(3))) void* sptr_t;

__device__ __forceinline__ u16 f2b(float f) {
  __hip_bfloat16 h = __float2bfloat16(f);
  return __builtin_bit_cast(u16, h);
}

// v_cvt_pk_bf16_f32: lo -> bits[15:0], hi -> bits[31:16]
__device__ __forceinline__ u32 cvtpk(float lo, float hi) {
  u32 r;
  asm volatile("v_cvt_pk_bf16_f32 %0, %1, %2" : "=v"(r) : "v"(lo), "v"(hi));
  return r;
}

// ---------------- fp32 -> bf16 convert (vectorized) ----------------
__global__ __launch_bounds__(256) void cvt_kernel(const float* __restrict__ src,
                                                  u16* __restrict__ dst, int n4) {
  int i = blockIdx.x * blockDim.x + threadIdx.x;
  int stride = gridDim.x * blockDim.x;
  for (; i < n4; i += stride) {
    float4 f = ((const float4*)src)[i];
    ushort4 o;
    o.x = f2b(f.x); o.y = f2b(f.y); o.z = f2b(f.z); o.w = f2b(f.w);
    ((ushort4*)dst)[i] = o;
  }
}

// ---------------- transpose + convert: src[K][N] fp32 -> dst[N][K] bf16 ----------------
__global__ __launch_bounds__(256) void tr_cvt(const float* __restrict__ src,
                                              u16* __restrict__ dst, int K, int N) {
  __shared__ u16 tile[64][72];   // +8 pad
  int k0 = blockIdx.x * 64, n0 = blockIdx.y * 64;
  #pragma unroll
  for (int t = 0; t < 16; ++t) {
    int idx = threadIdx.x + t * 256;
    int r = idx >> 6, c = idx & 63;
    tile[r][c] = f2b(src[(size_t)(k0 + r) * N + n0 + c]);
  }
  __syncthreads();
  #pragma unroll
  for (int t = 0; t < 16; ++t) {
    int idx = threadIdx.x + t * 256;
    int r = idx >> 6, c = idx & 63;       // r = local n, c = local k
    dst[(size_t)(n0 + r) * K + k0 + c] = tile[c][r];
  }
}

// ---------------- GEMM: C[M][N] = A[M][K] * Bt[N][K]^T + bias ----------------
// BM=256 x BN=128, BK=32, 4 waves each owning 128x64 (acc 8x4).
// 3-deep LDS pipeline, counted vmcnt(6) at tile boundary (T4), and a
// 2-phase-per-tile schedule (T3): each phase = {ds_read subtile || issue 3
// next-next-tile gloads -> s_barrier -> lgkmcnt(0)+sched_barrier ->
// setprio(1) 16 MFMA setprio(0)}. Phase-offset waves/blocks let the LDS
// pipe and MFMA pipe overlap instead of alternating in lockstep (T5).
// Granule-XOR swizzle via pre-swizzled global source + swizzled ds_read.
// EPI 0: scatter to q (scaled) / k / v^T.  EPI 1: fp32 out [M][N].
template <int EPI>
__global__ __launch_bounds__(256, 2) void gemm_bt(const u16* __restrict__ A,
                                                  const u16* __restrict__ Bt,
                                                  const float* __restrict__ bias,
                                                  int K, int N,
                                                  u16* __restrict__ out_qkv,
                                                  float* __restrict__ out_f) {
  __shared__ __align__(16) u16 As[3][256 * 32];
  __shared__ __align__(16) u16 Bs[3][128 * 32];
  const int tid = threadIdx.x;
  const int wave = tid >> 6, lane = tid & 63;
  const int lr = lane & 15, lk = lane >> 4;

  const int m0 = blockIdx.x * 256, n0 = blockIdx.y * 128;
  const int wr = (wave >> 1) * 128, wc = (wave & 1) * 64;

  f32x4 acc[8][4] = {};

  // full stage = 6 gloads/thread: A chunks 0-3, B chunks 0-1. Split 3+3.
  auto stage_lo = [&](int buf, int it) {         // A chunks 0-2
    const int kt = it * 32;
    #pragma unroll
    for (int i = 0; i < 3; ++i) {
      int ch = i * 256 + wave * 64 + lane;
      int row = ch >> 2;
      int gsrc = (ch & 3) ^ ((row >> 1) & 3);
      __builtin_amdgcn_global_load_lds((gptr_t)(A + (size_t)(m0 + row) * K + kt + gsrc * 8),
                                       (sptr_t)(&As[buf][ch * 8]), 16, 0, 0);
    }
  };
  auto stage_hi = [&](int buf, int it) {         // A chunk 3 + B chunks 0-1
    const int kt = it * 32;
    {
      int ch = 3 * 256 + wave * 64 + lane;
      int row = ch >> 2;
      int gsrc = (ch & 3) ^ ((row >> 1) & 3);
      __builtin_amdgcn_global_load_lds((gptr_t)(A + (size_t)(m0 + row) * K + kt + gsrc * 8),
                                       (sptr_t)(&As[buf][ch * 8]), 16, 0, 0);
    }
    #pragma unroll
    for (int i = 0; i < 2; ++i) {
      int ch = i * 256 + wave * 64 + lane;
      int row = ch >> 2;
      int gsrc = (ch & 3) ^ ((row >> 1) & 3);
      __builtin_amdgcn_global_load_lds((gptr_t)(Bt + (size_t)(n0 + row) * K + kt + gsrc * 8),
                                       (sptr_t)(&Bs[buf][ch * 8]), 16, 0, 0);
    }
  };

  const int KI = K / 32;                         // 32 iters (K=1024)
  stage_lo(0, 0); stage_hi(0, 0);
  stage_lo(1, 1); stage_hi(1, 1);
  asm volatile("s_waitcnt vmcnt(6)" ::: "memory");   // tile 0 complete
  __builtin_amdgcn_s_barrier();

  for (int it = 0; it < KI; ++it) {
    const int cur = it % 3;
    const bool pre = (it + 2 < KI);
    const int nbuf = (it + 2) % 3;

    // ---- phase 0: B frags + A-low frags, 3 prefetch gloads, 16 MFMA ----
    bf16x8 af0[4], af1[4], bfr[4];
    #pragma unroll
    for (int ni = 0; ni < 4; ++ni) {
      int r = wc + ni * 16 + lr;
      bfr[ni] = *(const bf16x8*)(&Bs[cur][r * 32 + ((lk ^ ((r >> 1) & 3)) << 3)]);
    }
    #pragma unroll
    for (int mi = 0; mi < 4; ++mi) {
      int r = wr + mi * 16 + lr;
      af0[mi] = *(const bf16x8*)(&As[cur][r * 32 + ((lk ^ ((r >> 1) & 3)) << 3)]);
    }
    if (pre) stage_lo(nbuf, it + 2);
    __builtin_amdgcn_s_barrier();
    asm volatile("s_waitcnt lgkmcnt(0)" ::: "memory");
    __builtin_amdgcn_sched_barrier(0);
    __builtin_amdgcn_s_setprio(1);
    #pragma unroll
    for (int mi = 0; mi < 4; ++mi)
      #pragma unroll
      for (int ni = 0; ni < 4; ++ni)
        acc[mi][ni] = __builtin_amdgcn_mfma_f32_16x16x32_bf16(af0[mi], bfr[ni], acc[mi][ni], 0, 0, 0);
    __builtin_amdgcn_s_setprio(0);

    // ---- phase 1: A-high frags, 3 prefetch gloads, 16 MFMA ----
    #pragma unroll
    for (int mi = 0; mi < 4; ++mi) {
      int r = wr + 64 + mi * 16 + lr;
      af1[mi] = *(const bf16x8*)(&As[cur][r * 32 + ((lk ^ ((r >> 1) & 3)) << 3)]);
    }
    if (pre) stage_hi(nbuf, it + 2);
    __builtin_amdgcn_s_barrier();
    asm volatile("s_waitcnt lgkmcnt(0)" ::: "memory");
    __builtin_amdgcn_sched_barrier(0);
    __builtin_amdgcn_s_setprio(1);
    #pragma unroll
    for (int mi = 0; mi < 4; ++mi)
      #pragma unroll
      for (int ni = 0; ni < 4; ++ni)
        acc[mi + 4][ni] = __builtin_amdgcn_mfma_f32_16x16x32_bf16(af1[mi], bfr[ni], acc[mi + 4][ni], 0, 0, 0);
    __builtin_amdgcn_s_setprio(0);

    // ---- tile boundary: counted wait (t+1 landed, t+2 in flight) ----
    if (pre) asm volatile("s_waitcnt vmcnt(6)" ::: "memory");
    else     asm volatile("s_waitcnt vmcnt(0)" ::: "memory");
    __builtin_amdgcn_s_barrier();
  }

  if (EPI == 0) {
    const int sel = (n0 >> 10);                   // whole block same q/k/v segment
    #pragma unroll
    for (int mi = 0; mi < 8; ++mi) {
      #pragma unroll
      for (int ni = 0; ni < 4; ++ni) {
        int m = m0 + wr + mi * 16 + lk * 4;       // +j
        int n = n0 + wc + ni * 16 + lr;
        int rem = n & 1023, h = rem >> 6, d = rem & 63;
        int b = m >> 11, t = m & 2047;
        if (sel == 2) {                           // v^T: t contiguous -> ushort4
          ushort4 st;
          #pragma unroll
          for (int j = 0; j < 4; ++j)
            ((u16*)&st)[j] = f2b(acc[mi][ni][j] + bias[n]);
          *(ushort4*)(out_qkv + 2 * (size_t)QKVSZ +
                      (((size_t)(b * H_ + h) * HD_ + d) * T_ + t)) = st;
        } else {
          #pragma unroll
          for (int j = 0; j < 4; ++j) {
            float val = acc[mi][ni][j] + bias[n];
            if (sel == 0) val *= QSCALE;
            out_qkv[(size_t)sel * QKVSZ +
                    (((size_t)(b * H_ + h) * T_ + (t + j)) * HD_ + d)] = f2b(val);
          }
        }
      }
    }
  } else {
    #pragma unroll
    for (int mi = 0; mi < 8; ++mi)
      #pragma unroll
      for (int ni = 0; ni < 4; ++ni)
        #pragma unroll
        for (int j = 0; j < 4; ++j) {
          int m = m0 + wr + mi * 16 + lk * 4 + j;
          int n = n0 + wc + ni * 16 + lr;
          out_f[(size_t)m * C_ + n] = acc[mi][ni][j] + bias[n];
        }
  }
}

// ---------------- causal flash attention ----------------
// 128 threads = 2 waves; q-tile 64 (wave w owns q-rows [BQ+32w, BQ+32w+32)).
// grid (bh=64, 32 q-tiles) = 2048 blocks, heavy-first. 32x32x16 MFMAs,
// swapped S^T = mfma(K,Q). Softmax per-lane: raw v_exp_f32 (builtin exp2),
// cross-half reduce via __shfl_xor(32) (permlane32_swap(x,x) aliases the
// in-place swap when RA coalesces equal operands -> NOT usable for
// self-reduce). P in registers via cvt_pk + permlane32_swap (distinct
// operands -> safe). O^T = mfma(Vt, P). K/V dbuf + prefetch. setprio(1)
// around both MFMA clusters (m191: helps independent-phase attn blocks).
__global__ __launch_bounds__(128, 2) void attn_k(const u16* __restrict__ q,
                                                 const u16* __restrict__ k,
                                                 const u16* __restrict__ vt,
                                                 u16* __restrict__ y) {
  __shared__ __align__(16) u16 Ks[2][64 * 64];
  __shared__ __align__(16) u16 Vs[2][64 * 64];
  const int tid = threadIdx.x;
  const int wave = tid >> 6, lane = tid & 63;
  const int hi = lane >> 5, lq = lane & 31;
  const int qtb = gridDim.y - 1 - blockIdx.y;    // 31..0, heavy first
  const int bh = blockIdx.x;                     // fastest dim -> XCD spread
  const size_t koff = (size_t)bh * T_ * HD_;     // q,k: [bh][t][d]
  const size_t voff = (size_t)bh * HD_ * T_;     // vt:  [bh][d][t]
  const int qrow = qtb * 64 + 32 * wave + lq;    // this lane's q row (global)

  // Q B-frags (pre-scaled by 0.125*log2e): qf[c] = Q[qrow][16c+8hi .. +8]
  bf16x8 qf[4];
  #pragma unroll
  for (int c = 0; c < 4; ++c)
    qf[c] = *(const bf16x8*)(q + koff + (size_t)qrow * HD_ + 16 * c + 8 * hi);

  f32x16 o[2] = {};                              // [dh]: O^T rows 32dh..
  float mrun = -1e30f, lsum = 0.f;

  auto stage = [&](int buf, int kt) {
    const u16* kb = k + koff + (size_t)kt * 64 * HD_;
    const u16* vb = vt + voff + (size_t)kt * 64;
    #pragma unroll
    for (int j = 0; j < 4; ++j) {
      int cb = j * 128 + wave * 64;              // wave-uniform chunk base
      int ch = cb + lane;
      int row = ch >> 3, gg = ch & 7;
      int src = gg ^ (row & 7);                  // pre-swizzled global source
      __builtin_amdgcn_global_load_lds((gptr_t)(kb + row * HD_ + src * 8),
                                       (sptr_t)(&Ks[buf][cb * 8]), 16, 0, 0);
      __builtin_amdgcn_global_load_lds((gptr_t)(vb + (size_t)row * T_ + src * 8),
                                       (sptr_t)(&Vs[buf][cb * 8]), 16, 0, 0);
    }
  };

  const int nt = qtb + 1;
  stage(0, 0);
  __syncthreads();

  for (int kt = 0; kt < nt; ++kt) {
    const int cur = kt & 1;
    if (kt + 1 < nt) stage(cur ^ 1, kt + 1);
    const bool dia = (kt == qtb);
    const bool skip1 = dia && (wave == 0);       // kh=1 fully masked (wave-uniform)
    const u16* Kb = &Ks[cur][0];
    const u16* Vb = &Vs[cur][0];

    // ---- S^T = K Q^T ----
    f32x16 s[2] = {};
    __builtin_amdgcn_s_setprio(1);
    #pragma unroll
    for (int c = 0; c < 4; ++c) {
      #pragma unroll
      for (int kh = 0; kh < 2; ++kh) {
        if (kh == 1 && skip1) continue;
        int row = 32 * kh + lq;
        bf16x8 kf = *(const bf16x8*)(Kb + row * 64 + (((2 * c + hi) ^ (row & 7)) << 3));
        s[kh] = __builtin_amdgcn_mfma_f32_32x32x16_bf16(kf, qf[c], s[kh], 0, 0, 0);
      }
    }
    __builtin_amdgcn_s_setprio(0);

    if (dia) {
      // wave 0: kh0 diagonal-masked; wave 1: kh0 fully visible, kh1 diagonal-masked
      #pragma unroll
      for (int rr = 0; rr < 16; ++rr) {
        int kg = 64 * kt + 4 * hi + (rr & 3) + 8 * (rr >> 2);
        if (wave == 0) { if (kg > qrow) s[0][rr] = -1e30f; }
        else           { if (kg + 32 > qrow) s[1][rr] = -1e30f; }
      }
    }

    // ---- online softmax (lane and lane^32 share a q-row) ----
    // max tree in v_max3-fusible groups, short dep chains
    float g0, g1, g2, g3;
    {
      const f32x16& a = s[0];
      g0 = fmaxf(fmaxf(a[0], a[1]),   fmaxf(a[2], a[3]));
      g1 = fmaxf(fmaxf(a[4], a[5]),   fmaxf(a[6], a[7]));
      g2 = fmaxf(fmaxf(a[8], a[9]),   fmaxf(a[10], a[11]));
      g3 = fmaxf(fmaxf(a[12], a[13]), fmaxf(a[14], a[15]));
    }
    if (!skip1) {
      const f32x16& a = s[1];
      g0 = fmaxf(g0, fmaxf(fmaxf(a[0], a[1]),   fmaxf(a[2], a[3])));
      g1 = fmaxf(g1, fmaxf(fmaxf(a[4], a[5]),   fmaxf(a[6], a[7])));
      g2 = fmaxf(g2, fmaxf(fmaxf(a[8], a[9]),   fmaxf(a[10], a[11])));
      g3 = fmaxf(g3, fmaxf(fmaxf(a[12], a[13]), fmaxf(a[14], a[15])));
    }
    float tm = fmaxf(fmaxf(g0, g1), fmaxf(g2, g3));
    tm = fmaxf(tm, __shfl_xor(tm, 32));
    if (__any(tm > mrun + 8.f)) {                // defer-max (T13)
      float mn = fmaxf(mrun, tm);
      float al = __builtin_amdgcn_exp2f(mrun - mn);
      lsum *= al;
      o[0] *= al;
      o[1] *= al;
      mrun = mn;
    }
    float rs = 0.f;
    #pragma unroll
    for (int kh = 0; kh < 2; ++kh) {
      if (kh == 1 && skip1) continue;
      #pragma unroll
      for (int rr = 0; rr < 16; ++rr) {
        float p = __builtin_amdgcn_exp2f(s[kh][rr] - mrun);
        s[kh][rr] = p;
        rs += p;
      }
    }
    rs += __shfl_xor(rs, 32);
    lsum += rs;

    // ---- PV: O^T[d][q] += Vt P (P assembled in-register) ----
    #pragma unroll
    for (int kh = 0; kh < 2; ++kh) {
      if (kh == 1 && skip1) continue;
      bf16x8 pf[2];
      #pragma unroll
      for (int ct = 0; ct < 2; ++ct) {
        u32 A0 = cvtpk(s[kh][8 * ct + 0], s[kh][8 * ct + 1]);
        u32 A1 = cvtpk(s[kh][8 * ct + 2], s[kh][8 * ct + 3]);
        u32 B0 = cvtpk(s[kh][8 * ct + 4], s[kh][8 * ct + 5]);
        u32 B1 = cvtpk(s[kh][8 * ct + 6], s[kh][8 * ct + 7]);
        i32x2 r0 = __builtin_amdgcn_permlane32_swap((int)A0, (int)B0, false, false);
        i32x2 r1 = __builtin_amdgcn_permlane32_swap((int)A1, (int)B1, false, false);
        u32x4 w = {(u32)r0[0], (u32)r1[0], (u32)r0[1], (u32)r1[1]};
        pf[ct] = __builtin_bit_cast(bf16x8, w);
      }
      __builtin_amdgcn_s_setprio(1);
      #pragma unroll
      for (int ct = 0; ct < 2; ++ct)
        #pragma unroll
        for (int dh = 0; dh < 2; ++dh) {
          int row = 32 * dh + lq;
          bf16x8 vf = *(const bf16x8*)(Vb + row * 64 + (((4 * kh + 2 * ct + hi) ^ (row & 7)) << 3));
          o[dh] = __builtin_amdgcn_mfma_f32_32x32x16_bf16(vf, pf[ct], o[dh], 0, 0, 0);
        }
      __builtin_amdgcn_s_setprio(0);
    }
    __syncthreads();
  }

  // ---- epilogue: y[b,t,h*64+d] = O^T[d][q] / l ----
  const int b = bh >> 4, h = bh & 15;
  float li = 1.0f / lsum;
  u16* yrow = y + (size_t)(b * T_ + qrow) * C_ + h * 64;
  #pragma unroll
  for (int dh = 0; dh < 2; ++dh)
    #pragma unroll
    for (int u = 0; u < 4; ++u) {
      ushort4 st;
      st.x = f2b(o[dh][4 * u + 0] * li);
      st.y = f2b(o[dh][4 * u + 1] * li);
      st.z = f2b(o[dh][4 * u + 2] * li);
      st.w = f2b(o[dh][4 * u + 3] * li);
      *(ushort4*)(yrow + 32 * dh + 8 * u + 4 * hi) = st;
    }
}

extern "C" void kernel_launch(void* const* d_in, const int* in_sizes, int n_in,
                              void* d_out, int out_size, void* d_ws, size_t ws_size,
                              hipStream_t stream) {
  const float* x      = (const float*)d_in[0];
  const float* W_attn = (const float*)d_in[1];
  const float* b_attn = (const float*)d_in[2];
  const float* W_proj = (const float*)d_in[3];
  const float* b_proj = (const float*)d_in[4];
  float* out = (float*)d_out;

  u16* ws = (u16*)d_ws;
  u16* xb  = ws;
  u16* Wat = xb + (size_t)M_ * C_;
  u16* Wpt = Wat + (size_t)N3_ * C_;
  u16* qkv = Wpt + (size_t)C_ * C_;
  u16* y   = qkv + (size_t)3 * QKVSZ;

  cvt_kernel<<<2048, 256, 0, stream>>>(x, xb, M_ * C_ / 4);
  tr_cvt<<<dim3(C_ / 64, N3_ / 64), 256, 0, stream>>>(W_attn, Wat, C_, N3_);
  tr_cvt<<<dim3(C_ / 64, C_ / 64), 256, 0, stream>>>(W_proj, Wpt, C_, C_);
  gemm_bt<0><<<dim3(M_ / 256, N3_ / 128), 256, 0, stream>>>(xb, Wat, b_attn, C_, N3_, qkv, nullptr);
  attn_k<<<dim3(B_ * H_, T_ / 64), 128, 0, stream>>>(qkv, qkv + QKVSZ, qkv + 2 * QKVSZ, y);
  gemm_bt<1><<<dim3(M_ / 256, C_ / 128), 256, 0, stream>>>(y, Wpt, b_proj, C_, C_, nullptr, out);
}

// Round 10
// 175.596 us; speedup vs baseline: 1.2213x; 1.0383x over previous
//
#include <hip/hip_runtime.h>
#include <hip/hip_bf16.h>

#define B_ 4
#define T_ 2048
#define C_ 1024
#define H_ 16
#define HD_ 64
#define M_ (B_*T_)        // 8192 rows
#define N3_ (3*C_)        // 3072
#define QKVSZ (B_*H_*T_*HD_)  // 8388608 elems per tensor
#define QSCALE 0.1803368801f  // 0.125 * log2(e)

typedef unsigned short u16;
typedef unsigned int u32;
typedef __attribute__((ext_vector_type(8))) __bf16 bf16x8;
typedef __attribute__((ext_vector_type(4))) float f32x4;
typedef __attribute__((ext_vector_type(16))) float f32x16;
typedef __attribute__((ext_vector_type(2))) int i32x2;
typedef __attribute__((ext_vector_type(4))) u32 u32x4;
typedef const __attribute__((address_space(1))) void* gptr_t;
typedef __attribute__((address_space(3))) void* sptr_t;

__device__ __forceinline__ u16 f2b(float f) {
  __hip_bfloat16 h = __float2bfloat16(f);
  return __builtin_bit_cast(u16, h);
}

// v_cvt_pk_bf16_f32: lo -> bits[15:0], hi -> bits[31:16]
__device__ __forceinline__ u32 cvtpk(float lo, float hi) {
  u32 r;
  asm volatile("v_cvt_pk_bf16_f32 %0, %1, %2" : "=v"(r) : "v"(lo), "v"(hi));
  return r;
}

// ---------------- fp32 -> bf16 convert (vectorized) ----------------
__global__ __launch_bounds__(256) void cvt_kernel(const float* __restrict__ src,
                                                  u16* __restrict__ dst, int n4) {
  int i = blockIdx.x * blockDim.x + threadIdx.x;
  int stride = gridDim.x * blockDim.x;
  for (; i < n4; i += stride) {
    float4 f = ((const float4*)src)[i];
    ushort4 o;
    o.x = f2b(f.x); o.y = f2b(f.y); o.z = f2b(f.z); o.w = f2b(f.w);
    ((ushort4*)dst)[i] = o;
  }
}

// ---------------- transpose + convert: src[K][N] fp32 -> dst[N][K] bf16 ----------------
__global__ __launch_bounds__(256) void tr_cvt(const float* __restrict__ src,
                                              u16* __restrict__ dst, int K, int N) {
  __shared__ u16 tile[64][72];   // +8 pad
  int k0 = blockIdx.x * 64, n0 = blockIdx.y * 64;
  #pragma unroll
  for (int t = 0; t < 16; ++t) {
    int idx = threadIdx.x + t * 256;
    int r = idx >> 6, c = idx & 63;
    tile[r][c] = f2b(src[(size_t)(k0 + r) * N + n0 + c]);
  }
  __syncthreads();
  #pragma unroll
  for (int t = 0; t < 16; ++t) {
    int idx = threadIdx.x + t * 256;
    int r = idx >> 6, c = idx & 63;       // r = local n, c = local k
    dst[(size_t)(n0 + r) * K + k0 + c] = tile[c][r];
  }
}

// ---------------- GEMM: C[M][N] = A[M][K] * Bt[N][K]^T + bias ----------------
// BM=128 x BN=128, BK=32, 4 waves (2x2), per-wave 64x64 (acc 4x4 = 64 regs;
// combined reg footprint ~115 -> 4 waves/SIMD; 2-buffer LDS = 32KB -> ~4
// blocks/CU = 16 waves/CU, 2x the round-9 occupancy; m97-proven geometry).
// Depth-2 prefetch with 2 buffers: read all 8 frags -> lgkmcnt(0)+barrier
// (buf[cur] free) -> stage(t+2) into buf[cur] -> MFMA -> counted vmcnt(4)
// (t+1 landed, t+2 in flight) + barrier. 2 barriers/iter.
// Granule-XOR swizzle via pre-swizzled global source + swizzled ds_read.
// EPI 0: scatter to q (scaled) / k / v^T.  EPI 1: fp32 out [M][N].
template <int EPI>
__global__ __launch_bounds__(256, 3) void gemm_bt(const u16* __restrict__ A,
                                                  const u16* __restrict__ Bt,
                                                  const float* __restrict__ bias,
                                                  int K, int N,
                                                  u16* __restrict__ out_qkv,
                                                  float* __restrict__ out_f) {
  __shared__ __align__(16) u16 As[2][128 * 32];
  __shared__ __align__(16) u16 Bs[2][128 * 32];
  const int tid = threadIdx.x;
  const int wave = tid >> 6, lane = tid & 63;
  const int lr = lane & 15, lk = lane >> 4;

  const int m0 = blockIdx.x * 128, n0 = blockIdx.y * 128;
  const int wr = (wave >> 1) * 64, wc = (wave & 1) * 64;

  f32x4 acc[4][4] = {};

  auto stage = [&](int buf, int it) {            // 4 gloads/thread (2 A + 2 B)
    const int kt = it * 32;
    #pragma unroll
    for (int i = 0; i < 2; ++i) {
      int ch = i * 256 + tid;                    // A: 512 chunks
      int row = ch >> 2;
      int gsrc = (ch & 3) ^ ((row >> 1) & 3);
      __builtin_amdgcn_global_load_lds((gptr_t)(A + (size_t)(m0 + row) * K + kt + gsrc * 8),
                                       (sptr_t)(&As[buf][ch * 8]), 16, 0, 0);
    }
    #pragma unroll
    for (int i = 0; i < 2; ++i) {
      int ch = i * 256 + tid;                    // B: 512 chunks
      int row = ch >> 2;
      int gsrc = (ch & 3) ^ ((row >> 1) & 3);
      __builtin_amdgcn_global_load_lds((gptr_t)(Bt + (size_t)(n0 + row) * K + kt + gsrc * 8),
                                       (sptr_t)(&Bs[buf][ch * 8]), 16, 0, 0);
    }
  };

  const int KI = K / 32;                         // 32 iters (K=1024)
  stage(0, 0);
  stage(1, 1);
  asm volatile("s_waitcnt vmcnt(4)" ::: "memory");   // tile 0 complete
  __builtin_amdgcn_s_barrier();

  for (int it = 0; it < KI; ++it) {
    const int cur = it & 1;
    const bool pre = (it + 2 < KI);

    // ---- read all frags of tile t (8 ds_read_b128) ----
    bf16x8 af[4], bfr[4];
    #pragma unroll
    for (int mi = 0; mi < 4; ++mi) {
      int r = wr + mi * 16 + lr;
      af[mi] = *(const bf16x8*)(&As[cur][r * 32 + ((lk ^ ((r >> 1) & 3)) << 3)]);
    }
    #pragma unroll
    for (int ni = 0; ni < 4; ++ni) {
      int r = wc + ni * 16 + lr;
      bfr[ni] = *(const bf16x8*)(&Bs[cur][r * 32 + ((lk ^ ((r >> 1) & 3)) << 3)]);
    }
    asm volatile("s_waitcnt lgkmcnt(0)" ::: "memory");
    __builtin_amdgcn_sched_barrier(0);
    __builtin_amdgcn_s_barrier();                // all waves done reading buf[cur]

    if (pre) stage(cur, it + 2);                 // refill just-freed buffer

    __builtin_amdgcn_s_setprio(1);
    #pragma unroll
    for (int mi = 0; mi < 4; ++mi)
      #pragma unroll
      for (int ni = 0; ni < 4; ++ni)
        acc[mi][ni] = __builtin_amdgcn_mfma_f32_16x16x32_bf16(af[mi], bfr[ni], acc[mi][ni], 0, 0, 0);
    __builtin_amdgcn_s_setprio(0);

    // ---- tile boundary: counted wait (t+1 landed, t+2 in flight) ----
    if (pre) asm volatile("s_waitcnt vmcnt(4)" ::: "memory");
    else     asm volatile("s_waitcnt vmcnt(0)" ::: "memory");
    __builtin_amdgcn_s_barrier();
  }

  if (EPI == 0) {
    const int sel = (n0 >> 10);                   // whole block same q/k/v segment
    #pragma unroll
    for (int mi = 0; mi < 4; ++mi) {
      #pragma unroll
      for (int ni = 0; ni < 4; ++ni) {
        int m = m0 + wr + mi * 16 + lk * 4;       // +j
        int n = n0 + wc + ni * 16 + lr;
        int rem = n & 1023, h = rem >> 6, d = rem & 63;
        int b = m >> 11, t = m & 2047;
        if (sel == 2) {                           // v^T: t contiguous -> ushort4
          ushort4 st;
          #pragma unroll
          for (int j = 0; j < 4; ++j)
            ((u16*)&st)[j] = f2b(acc[mi][ni][j] + bias[n]);
          *(ushort4*)(out_qkv + 2 * (size_t)QKVSZ +
                      (((size_t)(b * H_ + h) * HD_ + d) * T_ + t)) = st;
        } else {
          #pragma unroll
          for (int j = 0; j < 4; ++j) {
            float val = acc[mi][ni][j] + bias[n];
            if (sel == 0) val *= QSCALE;
            out_qkv[(size_t)sel * QKVSZ +
                    (((size_t)(b * H_ + h) * T_ + (t + j)) * HD_ + d)] = f2b(val);
          }
        }
      }
    }
  } else {
    #pragma unroll
    for (int mi = 0; mi < 4; ++mi)
      #pragma unroll
      for (int ni = 0; ni < 4; ++ni)
        #pragma unroll
        for (int j = 0; j < 4; ++j) {
          int m = m0 + wr + mi * 16 + lk * 4 + j;
          int n = n0 + wc + ni * 16 + lr;
          out_f[(size_t)m * C_ + n] = acc[mi][ni][j] + bias[n];
        }
  }
}

// ---------------- causal flash attention ----------------
// 128 threads = 2 waves; q-tile 64 (wave w owns q-rows [BQ+32w, BQ+32w+32)).
// grid (bh=64, 32 q-tiles) = 2048 blocks, heavy-first. 32x32x16 MFMAs,
// swapped S^T = mfma(K,Q). Softmax per-lane: raw v_exp_f32 (builtin exp2),
// cross-half reduce via __shfl_xor(32) (permlane32_swap(x,x) aliases the
// in-place swap when RA coalesces equal operands -> NOT usable for
// self-reduce). P in registers via cvt_pk + permlane32_swap (distinct
// operands -> safe). O^T = mfma(Vt, P). K/V dbuf + prefetch. setprio(1)
// around both MFMA clusters (m191: helps independent-phase attn blocks).
__global__ __launch_bounds__(128, 2) void attn_k(const u16* __restrict__ q,
                                                 const u16* __restrict__ k,
                                                 const u16* __restrict__ vt,
                                                 u16* __restrict__ y) {
  __shared__ __align__(16) u16 Ks[2][64 * 64];
  __shared__ __align__(16) u16 Vs[2][64 * 64];
  const int tid = threadIdx.x;
  const int wave = tid >> 6, lane = tid & 63;
  const int hi = lane >> 5, lq = lane & 31;
  const int qtb = gridDim.y - 1 - blockIdx.y;    // 31..0, heavy first
  const int bh = blockIdx.x;                     // fastest dim -> XCD spread
  const size_t koff = (size_t)bh * T_ * HD_;     // q,k: [bh][t][d]
  const size_t voff = (size_t)bh * HD_ * T_;     // vt:  [bh][d][t]
  const int qrow = qtb * 64 + 32 * wave + lq;    // this lane's q row (global)

  // Q B-frags (pre-scaled by 0.125*log2e): qf[c] = Q[qrow][16c+8hi .. +8]
  bf16x8 qf[4];
  #pragma unroll
  for (int c = 0; c < 4; ++c)
    qf[c] = *(const bf16x8*)(q + koff + (size_t)qrow * HD_ + 16 * c + 8 * hi);

  f32x16 o[2] = {};                              // [dh]: O^T rows 32dh..
  float mrun = -1e30f, lsum = 0.f;

  auto stage = [&](int buf, int kt) {
    const u16* kb = k + koff + (size_t)kt * 64 * HD_;
    const u16* vb = vt + voff + (size_t)kt * 64;
    #pragma unroll
    for (int j = 0; j < 4; ++j) {
      int cb = j * 128 + wave * 64;              // wave-uniform chunk base
      int ch = cb + lane;
      int row = ch >> 3, gg = ch & 7;
      int src = gg ^ (row & 7);                  // pre-swizzled global source
      __builtin_amdgcn_global_load_lds((gptr_t)(kb + row * HD_ + src * 8),
                                       (sptr_t)(&Ks[buf][cb * 8]), 16, 0, 0);
      __builtin_amdgcn_global_load_lds((gptr_t)(vb + (size_t)row * T_ + src * 8),
                                       (sptr_t)(&Vs[buf][cb * 8]), 16, 0, 0);
    }
  };

  const int nt = qtb + 1;
  stage(0, 0);
  __syncthreads();

  for (int kt = 0; kt < nt; ++kt) {
    const int cur = kt & 1;
    if (kt + 1 < nt) stage(cur ^ 1, kt + 1);
    const bool dia = (kt == qtb);
    const bool skip1 = dia && (wave == 0);       // kh=1 fully masked (wave-uniform)
    const u16* Kb = &Ks[cur][0];
    const u16* Vb = &Vs[cur][0];

    // ---- S^T = K Q^T ----
    f32x16 s[2] = {};
    __builtin_amdgcn_s_setprio(1);
    #pragma unroll
    for (int c = 0; c < 4; ++c) {
      #pragma unroll
      for (int kh = 0; kh < 2; ++kh) {
        if (kh == 1 && skip1) continue;
        int row = 32 * kh + lq;
        bf16x8 kf = *(const bf16x8*)(Kb + row * 64 + (((2 * c + hi) ^ (row & 7)) << 3));
        s[kh] = __builtin_amdgcn_mfma_f32_32x32x16_bf16(kf, qf[c], s[kh], 0, 0, 0);
      }
    }
    __builtin_amdgcn_s_setprio(0);

    if (dia) {
      // wave 0: kh0 diagonal-masked; wave 1: kh0 fully visible, kh1 diagonal-masked
      #pragma unroll
      for (int rr = 0; rr < 16; ++rr) {
        int kg = 64 * kt + 4 * hi + (rr & 3) + 8 * (rr >> 2);
        if (wave == 0) { if (kg > qrow) s[0][rr] = -1e30f; }
        else           { if (kg + 32 > qrow) s[1][rr] = -1e30f; }
      }
    }

    // ---- online softmax (lane and lane^32 share a q-row) ----
    // max tree in v_max3-fusible groups, short dep chains
    float g0, g1, g2, g3;
    {
      const f32x16& a = s[0];
      g0 = fmaxf(fmaxf(a[0], a[1]),   fmaxf(a[2], a[3]));
      g1 = fmaxf(fmaxf(a[4], a[5]),   fmaxf(a[6], a[7]));
      g2 = fmaxf(fmaxf(a[8], a[9]),   fmaxf(a[10], a[11]));
      g3 = fmaxf(fmaxf(a[12], a[13]), fmaxf(a[14], a[15]));
    }
    if (!skip1) {
      const f32x16& a = s[1];
      g0 = fmaxf(g0, fmaxf(fmaxf(a[0], a[1]),   fmaxf(a[2], a[3])));
      g1 = fmaxf(g1, fmaxf(fmaxf(a[4], a[5]),   fmaxf(a[6], a[7])));
      g2 = fmaxf(g2, fmaxf(fmaxf(a[8], a[9]),   fmaxf(a[10], a[11])));
      g3 = fmaxf(g3, fmaxf(fmaxf(a[12], a[13]), fmaxf(a[14], a[15])));
    }
    float tm = fmaxf(fmaxf(g0, g1), fmaxf(g2, g3));
    tm = fmaxf(tm, __shfl_xor(tm, 32));
    if (__any(tm > mrun + 8.f)) {                // defer-max (T13)
      float mn = fmaxf(mrun, tm);
      float al = __builtin_amdgcn_exp2f(mrun - mn);
      lsum *= al;
      o[0] *= al;
      o[1] *= al;
      mrun = mn;
    }
    float rs = 0.f;
    #pragma unroll
    for (int kh = 0; kh < 2; ++kh) {
      if (kh == 1 && skip1) continue;
      #pragma unroll
      for (int rr = 0; rr < 16; ++rr) {
        float p = __builtin_amdgcn_exp2f(s[kh][rr] - mrun);
        s[kh][rr] = p;
        rs += p;
      }
    }
    rs += __shfl_xor(rs, 32);
    lsum += rs;

    // ---- PV: O^T[d][q] += Vt P (P assembled in-register) ----
    #pragma unroll
    for (int kh = 0; kh < 2; ++kh) {
      if (kh == 1 && skip1) continue;
      bf16x8 pf[2];
      #pragma unroll
      for (int ct = 0; ct < 2; ++ct) {
        u32 A0 = cvtpk(s[kh][8 * ct + 0], s[kh][8 * ct + 1]);
        u32 A1 = cvtpk(s[kh][8 * ct + 2], s[kh][8 * ct + 3]);
        u32 B0 = cvtpk(s[kh][8 * ct + 4], s[kh][8 * ct + 5]);
        u32 B1 = cvtpk(s[kh][8 * ct + 6], s[kh][8 * ct + 7]);
        i32x2 r0 = __builtin_amdgcn_permlane32_swap((int)A0, (int)B0, false, false);
        i32x2 r1 = __builtin_amdgcn_permlane32_swap((int)A1, (int)B1, false, false);
        u32x4 w = {(u32)r0[0], (u32)r1[0], (u32)r0[1], (u32)r1[1]};
        pf[ct] = __builtin_bit_cast(bf16x8, w);
      }
      __builtin_amdgcn_s_setprio(1);
      #pragma unroll
      for (int ct = 0; ct < 2; ++ct)
        #pragma unroll
        for (int dh = 0; dh < 2; ++dh) {
          int row = 32 * dh + lq;
          bf16x8 vf = *(const bf16x8*)(Vb + row * 64 + (((4 * kh + 2 * ct + hi) ^ (row & 7)) << 3));
          o[dh] = __builtin_amdgcn_mfma_f32_32x32x16_bf16(vf, pf[ct], o[dh], 0, 0, 0);
        }
      __builtin_amdgcn_s_setprio(0);
    }
    __syncthreads();
  }

  // ---- epilogue: y[b,t,h*64+d] = O^T[d][q] / l ----
  const int b = bh >> 4, h = bh & 15;
  float li = 1.0f / lsum;
  u16* yrow = y + (size_t)(b * T_ + qrow) * C_ + h * 64;
  #pragma unroll
  for (int dh = 0; dh < 2; ++dh)
    #pragma unroll
    for (int u = 0; u < 4; ++u) {
      ushort4 st;
      st.x = f2b(o[dh][4 * u + 0] * li);
      st.y = f2b(o[dh][4 * u + 1] * li);
      st.z = f2b(o[dh][4 * u + 2] * li);
      st.w = f2b(o[dh][4 * u + 3] * li);
      *(ushort4*)(yrow + 32 * dh + 8 * u + 4 * hi) = st;
    }
}

extern "C" void kernel_launch(void* const* d_in, const int* in_sizes, int n_in,
                              void* d_out, int out_size, void* d_ws, size_t ws_size,
                              hipStream_t stream) {
  const float* x      = (const float*)d_in[0];
  const float* W_attn = (const float*)d_in[1];
  const float* b_attn = (const float*)d_in[2];
  const float* W_proj = (const float*)d_in[3];
  const float* b_proj = (const float*)d_in[4];
  float* out = (float*)d_out;

  u16* ws = (u16*)d_ws;
  u16* xb  = ws;
  u16* Wat = xb + (size_t)M_ * C_;
  u16* Wpt = Wat + (size_t)N3_ * C_;
  u16* qkv = Wpt + (size_t)C_ * C_;
  u16* y   = qkv + (size_t)3 * QKVSZ;

  cvt_kernel<<<2048, 256, 0, stream>>>(x, xb, M_ * C_ / 4);
  tr_cvt<<<dim3(C_ / 64, N3_ / 64), 256, 0, stream>>>(W_attn, Wat, C_, N3_);
  tr_cvt<<<dim3(C_ / 64, C_ / 64), 256, 0, stream>>>(W_proj, Wpt, C_, C_);
  gemm_bt<0><<<dim3(M_ / 128, N3_ / 128), 256, 0, stream>>>(xb, Wat, b_attn, C_, N3_, qkv, nullptr);
  attn_k<<<dim3(B_ * H_, T_ / 64), 128, 0, stream>>>(qkv, qkv + QKVSZ, qkv + 2 * QKVSZ, y);
  gemm_bt<1><<<dim3(M_ / 128, C_ / 128), 256, 0, stream>>>(y, Wpt, b_proj, C_, C_, nullptr, out);
}

// Round 11
// 174.577 us; speedup vs baseline: 1.2284x; 1.0058x over previous
//
#include <hip/hip_runtime.h>
#include <hip/hip_bf16.h>

#define B_ 4
#define T_ 2048
#define C_ 1024
#define H_ 16
#define HD_ 64
#define M_ (B_*T_)        // 8192 rows
#define N3_ (3*C_)        // 3072
#define QKVSZ (B_*H_*T_*HD_)  // 8388608 elems per tensor
#define QSCALE 0.1803368801f  // 0.125 * log2(e)

typedef unsigned short u16;
typedef unsigned int u32;
typedef __attribute__((ext_vector_type(8))) __bf16 bf16x8;
typedef __attribute__((ext_vector_type(4))) float f32x4;
typedef __attribute__((ext_vector_type(16))) float f32x16;
typedef __attribute__((ext_vector_type(2))) int i32x2;
typedef __attribute__((ext_vector_type(4))) u32 u32x4;
typedef const __attribute__((address_space(1))) void* gptr_t;
typedef __attribute__((address_space(3))) void* sptr_t;

__device__ __forceinline__ u16 f2b(float f) {
  __hip_bfloat16 h = __float2bfloat16(f);
  return __builtin_bit_cast(u16, h);
}

// v_cvt_pk_bf16_f32: lo -> bits[15:0], hi -> bits[31:16]
__device__ __forceinline__ u32 cvtpk(float lo, float hi) {
  u32 r;
  asm volatile("v_cvt_pk_bf16_f32 %0, %1, %2" : "=v"(r) : "v"(lo), "v"(hi));
  return r;
}

// ---------------- fp32 -> bf16 convert (vectorized) ----------------
__global__ __launch_bounds__(256) void cvt_kernel(const float* __restrict__ src,
                                                  u16* __restrict__ dst, int n4) {
  int i = blockIdx.x * blockDim.x + threadIdx.x;
  int stride = gridDim.x * blockDim.x;
  for (; i < n4; i += stride) {
    float4 f = ((const float4*)src)[i];
    ushort4 o;
    o.x = f2b(f.x); o.y = f2b(f.y); o.z = f2b(f.z); o.w = f2b(f.w);
    ((ushort4*)dst)[i] = o;
  }
}

// ---------------- transpose + convert: src[K][N] fp32 -> dst[N][K] bf16 ----------------
__global__ __launch_bounds__(256) void tr_cvt(const float* __restrict__ src,
                                              u16* __restrict__ dst, int K, int N) {
  __shared__ u16 tile[64][72];   // +8 pad
  int k0 = blockIdx.x * 64, n0 = blockIdx.y * 64;
  #pragma unroll
  for (int t = 0; t < 16; ++t) {
    int idx = threadIdx.x + t * 256;
    int r = idx >> 6, c = idx & 63;
    tile[r][c] = f2b(src[(size_t)(k0 + r) * N + n0 + c]);
  }
  __syncthreads();
  #pragma unroll
  for (int t = 0; t < 16; ++t) {
    int idx = threadIdx.x + t * 256;
    int r = idx >> 6, c = idx & 63;       // r = local n, c = local k
    dst[(size_t)(n0 + r) * K + k0 + c] = tile[c][r];
  }
}

// ---------------- GEMM: C[M][N] = A[M][K] * Bt[N][K]^T + bias ----------------
// BM=128 x BN=128, BK=32, 4 waves (2x2), per-wave 64x64 (acc 4x4).
// 3-buffer single-barrier pipeline: at iter t, stage(t+2) -> buf[(t+2)%3]
// (= buf[(t-1)%3], freed by iter t-1's end barrier: all reads of it happened
// before that barrier, so async gload_lds writes landing later are safe).
// Order: stage FIRST (T3 recipe) -> 8 frag ds_reads -> lgkmcnt(0) -> MFMA ->
// counted vmcnt(4) (t+1 landed, t+2 in flight) -> ONE s_barrier per iter.
// No mid-iteration barrier => waves skew and LDS/MFMA pipes interleave.
// Granule-XOR swizzle via pre-swizzled global source + swizzled ds_read.
// EPI 0: scatter to q (scaled) / k / v^T.  EPI 1: fp32 out [M][N].
template <int EPI>
__global__ __launch_bounds__(256, 3) void gemm_bt(const u16* __restrict__ A,
                                                  const u16* __restrict__ Bt,
                                                  const float* __restrict__ bias,
                                                  int K, int N,
                                                  u16* __restrict__ out_qkv,
                                                  float* __restrict__ out_f) {
  __shared__ __align__(16) u16 As[3][128 * 32];
  __shared__ __align__(16) u16 Bs[3][128 * 32];
  const int tid = threadIdx.x;
  const int wave = tid >> 6, lane = tid & 63;
  const int lr = lane & 15, lk = lane >> 4;

  const int m0 = blockIdx.x * 128, n0 = blockIdx.y * 128;
  const int wr = (wave >> 1) * 64, wc = (wave & 1) * 64;

  f32x4 acc[4][4] = {};

  auto stage = [&](int buf, int it) {            // 4 gloads/thread (2 A + 2 B)
    const int kt = it * 32;
    #pragma unroll
    for (int i = 0; i < 2; ++i) {
      int ch = i * 256 + tid;                    // A: 512 chunks
      int row = ch >> 2;
      int gsrc = (ch & 3) ^ ((row >> 1) & 3);
      __builtin_amdgcn_global_load_lds((gptr_t)(A + (size_t)(m0 + row) * K + kt + gsrc * 8),
                                       (sptr_t)(&As[buf][ch * 8]), 16, 0, 0);
    }
    #pragma unroll
    for (int i = 0; i < 2; ++i) {
      int ch = i * 256 + tid;                    // B: 512 chunks
      int row = ch >> 2;
      int gsrc = (ch & 3) ^ ((row >> 1) & 3);
      __builtin_amdgcn_global_load_lds((gptr_t)(Bt + (size_t)(n0 + row) * K + kt + gsrc * 8),
                                       (sptr_t)(&Bs[buf][ch * 8]), 16, 0, 0);
    }
  };

  const int KI = K / 32;                         // 32 iters (K=1024)
  stage(0, 0);
  stage(1, 1);
  asm volatile("s_waitcnt vmcnt(4)" ::: "memory");   // tile 0 complete
  __builtin_amdgcn_s_barrier();

  for (int it = 0; it < KI; ++it) {
    const int cur = it % 3;
    const bool pre = (it + 2 < KI);
    if (pre) stage((it + 2) % 3, it + 2);        // into buffer freed last iter

    // ---- read all frags of tile t (8 ds_read_b128) ----
    bf16x8 af[4], bfr[4];
    #pragma unroll
    for (int mi = 0; mi < 4; ++mi) {
      int r = wr + mi * 16 + lr;
      af[mi] = *(const bf16x8*)(&As[cur][r * 32 + ((lk ^ ((r >> 1) & 3)) << 3)]);
    }
    #pragma unroll
    for (int ni = 0; ni < 4; ++ni) {
      int r = wc + ni * 16 + lr;
      bfr[ni] = *(const bf16x8*)(&Bs[cur][r * 32 + ((lk ^ ((r >> 1) & 3)) << 3)]);
    }
    asm volatile("s_waitcnt lgkmcnt(0)" ::: "memory");
    __builtin_amdgcn_sched_barrier(0);

    __builtin_amdgcn_s_setprio(1);
    #pragma unroll
    for (int mi = 0; mi < 4; ++mi)
      #pragma unroll
      for (int ni = 0; ni < 4; ++ni)
        acc[mi][ni] = __builtin_amdgcn_mfma_f32_16x16x32_bf16(af[mi], bfr[ni], acc[mi][ni], 0, 0, 0);
    __builtin_amdgcn_s_setprio(0);

    // ---- tile boundary: counted wait (t+1 landed, t+2 in flight) ----
    if (pre) asm volatile("s_waitcnt vmcnt(4)" ::: "memory");
    else     asm volatile("s_waitcnt vmcnt(0)" ::: "memory");
    __builtin_amdgcn_s_barrier();
  }

  if (EPI == 0) {
    const int sel = (n0 >> 10);                   // whole block same q/k/v segment
    #pragma unroll
    for (int mi = 0; mi < 4; ++mi) {
      #pragma unroll
      for (int ni = 0; ni < 4; ++ni) {
        int m = m0 + wr + mi * 16 + lk * 4;       // +j
        int n = n0 + wc + ni * 16 + lr;
        int rem = n & 1023, h = rem >> 6, d = rem & 63;
        int b = m >> 11, t = m & 2047;
        if (sel == 2) {                           // v^T: t contiguous -> ushort4
          ushort4 st;
          #pragma unroll
          for (int j = 0; j < 4; ++j)
            ((u16*)&st)[j] = f2b(acc[mi][ni][j] + bias[n]);
          *(ushort4*)(out_qkv + 2 * (size_t)QKVSZ +
                      (((size_t)(b * H_ + h) * HD_ + d) * T_ + t)) = st;
        } else {
          #pragma unroll
          for (int j = 0; j < 4; ++j) {
            float val = acc[mi][ni][j] + bias[n];
            if (sel == 0) val *= QSCALE;
            out_qkv[(size_t)sel * QKVSZ +
                    (((size_t)(b * H_ + h) * T_ + (t + j)) * HD_ + d)] = f2b(val);
          }
        }
      }
    }
  } else {
    #pragma unroll
    for (int mi = 0; mi < 4; ++mi)
      #pragma unroll
      for (int ni = 0; ni < 4; ++ni)
        #pragma unroll
        for (int j = 0; j < 4; ++j) {
          int m = m0 + wr + mi * 16 + lk * 4 + j;
          int n = n0 + wc + ni * 16 + lr;
          out_f[(size_t)m * C_ + n] = acc[mi][ni][j] + bias[n];
        }
  }
}

// ---------------- causal flash attention ----------------
// 128 threads = 2 waves; q-tile 64 (wave w owns q-rows [BQ+32w, BQ+32w+32)).
// grid (bh=64, 32 q-tiles) = 2048 blocks, heavy-first. 32x32x16 MFMAs,
// swapped S^T = mfma(K,Q). Softmax per-lane: raw v_exp_f32 (builtin exp2),
// cross-half reduce via __shfl_xor(32) (permlane32_swap(x,x) aliases the
// in-place swap when RA coalesces equal operands -> NOT usable for
// self-reduce). P in registers via cvt_pk + permlane32_swap (distinct
// operands -> safe). O^T = mfma(Vt, P). K/V dbuf + prefetch. setprio(1)
// around both MFMA clusters (m191: helps independent-phase attn blocks).
__global__ __launch_bounds__(128, 2) void attn_k(const u16* __restrict__ q,
                                                 const u16* __restrict__ k,
                                                 const u16* __restrict__ vt,
                                                 u16* __restrict__ y) {
  __shared__ __align__(16) u16 Ks[2][64 * 64];
  __shared__ __align__(16) u16 Vs[2][64 * 64];
  const int tid = threadIdx.x;
  const int wave = tid >> 6, lane = tid & 63;
  const int hi = lane >> 5, lq = lane & 31;
  const int qtb = gridDim.y - 1 - blockIdx.y;    // 31..0, heavy first
  const int bh = blockIdx.x;                     // fastest dim -> XCD spread
  const size_t koff = (size_t)bh * T_ * HD_;     // q,k: [bh][t][d]
  const size_t voff = (size_t)bh * HD_ * T_;     // vt:  [bh][d][t]
  const int qrow = qtb * 64 + 32 * wave + lq;    // this lane's q row (global)

  // Q B-frags (pre-scaled by 0.125*log2e): qf[c] = Q[qrow][16c+8hi .. +8]
  bf16x8 qf[4];
  #pragma unroll
  for (int c = 0; c < 4; ++c)
    qf[c] = *(const bf16x8*)(q + koff + (size_t)qrow * HD_ + 16 * c + 8 * hi);

  f32x16 o[2] = {};                              // [dh]: O^T rows 32dh..
  float mrun = -1e30f, lsum = 0.f;

  auto stage = [&](int buf, int kt) {
    const u16* kb = k + koff + (size_t)kt * 64 * HD_;
    const u16* vb = vt + voff + (size_t)kt * 64;
    #pragma unroll
    for (int j = 0; j < 4; ++j) {
      int cb = j * 128 + wave * 64;              // wave-uniform chunk base
      int ch = cb + lane;
      int row = ch >> 3, gg = ch & 7;
      int src = gg ^ (row & 7);                  // pre-swizzled global source
      __builtin_amdgcn_global_load_lds((gptr_t)(kb + row * HD_ + src * 8),
                                       (sptr_t)(&Ks[buf][cb * 8]), 16, 0, 0);
      __builtin_amdgcn_global_load_lds((gptr_t)(vb + (size_t)row * T_ + src * 8),
                                       (sptr_t)(&Vs[buf][cb * 8]), 16, 0, 0);
    }
  };

  const int nt = qtb + 1;
  stage(0, 0);
  __syncthreads();

  for (int kt = 0; kt < nt; ++kt) {
    const int cur = kt & 1;
    if (kt + 1 < nt) stage(cur ^ 1, kt + 1);
    const bool dia = (kt == qtb);
    const bool skip1 = dia && (wave == 0);       // kh=1 fully masked (wave-uniform)
    const u16* Kb = &Ks[cur][0];
    const u16* Vb = &Vs[cur][0];

    // ---- S^T = K Q^T ----
    f32x16 s[2] = {};
    __builtin_amdgcn_s_setprio(1);
    #pragma unroll
    for (int c = 0; c < 4; ++c) {
      #pragma unroll
      for (int kh = 0; kh < 2; ++kh) {
        if (kh == 1 && skip1) continue;
        int row = 32 * kh + lq;
        bf16x8 kf = *(const bf16x8*)(Kb + row * 64 + (((2 * c + hi) ^ (row & 7)) << 3));
        s[kh] = __builtin_amdgcn_mfma_f32_32x32x16_bf16(kf, qf[c], s[kh], 0, 0, 0);
      }
    }
    __builtin_amdgcn_s_setprio(0);

    if (dia) {
      // wave 0: kh0 diagonal-masked; wave 1: kh0 fully visible, kh1 diagonal-masked
      #pragma unroll
      for (int rr = 0; rr < 16; ++rr) {
        int kg = 64 * kt + 4 * hi + (rr & 3) + 8 * (rr >> 2);
        if (wave == 0) { if (kg > qrow) s[0][rr] = -1e30f; }
        else           { if (kg + 32 > qrow) s[1][rr] = -1e30f; }
      }
    }

    // ---- online softmax (lane and lane^32 share a q-row) ----
    // max tree in v_max3-fusible groups, short dep chains
    float g0, g1, g2, g3;
    {
      const f32x16& a = s[0];
      g0 = fmaxf(fmaxf(a[0], a[1]),   fmaxf(a[2], a[3]));
      g1 = fmaxf(fmaxf(a[4], a[5]),   fmaxf(a[6], a[7]));
      g2 = fmaxf(fmaxf(a[8], a[9]),   fmaxf(a[10], a[11]));
      g3 = fmaxf(fmaxf(a[12], a[13]), fmaxf(a[14], a[15]));
    }
    if (!skip1) {
      const f32x16& a = s[1];
      g0 = fmaxf(g0, fmaxf(fmaxf(a[0], a[1]),   fmaxf(a[2], a[3])));
      g1 = fmaxf(g1, fmaxf(fmaxf(a[4], a[5]),   fmaxf(a[6], a[7])));
      g2 = fmaxf(g2, fmaxf(fmaxf(a[8], a[9]),   fmaxf(a[10], a[11])));
      g3 = fmaxf(g3, fmaxf(fmaxf(a[12], a[13]), fmaxf(a[14], a[15])));
    }
    float tm = fmaxf(fmaxf(g0, g1), fmaxf(g2, g3));
    tm = fmaxf(tm, __shfl_xor(tm, 32));
    if (__any(tm > mrun + 8.f)) {                // defer-max (T13)
      float mn = fmaxf(mrun, tm);
      float al = __builtin_amdgcn_exp2f(mrun - mn);
      lsum *= al;
      o[0] *= al;
      o[1] *= al;
      mrun = mn;
    }
    float rs = 0.f;
    #pragma unroll
    for (int kh = 0; kh < 2; ++kh) {
      if (kh == 1 && skip1) continue;
      #pragma unroll
      for (int rr = 0; rr < 16; ++rr) {
        float p = __builtin_amdgcn_exp2f(s[kh][rr] - mrun);
        s[kh][rr] = p;
        rs += p;
      }
    }
    rs += __shfl_xor(rs, 32);
    lsum += rs;

    // ---- PV: O^T[d][q] += Vt P (P assembled in-register) ----
    #pragma unroll
    for (int kh = 0; kh < 2; ++kh) {
      if (kh == 1 && skip1) continue;
      bf16x8 pf[2];
      #pragma unroll
      for (int ct = 0; ct < 2; ++ct) {
        u32 A0 = cvtpk(s[kh][8 * ct + 0], s[kh][8 * ct + 1]);
        u32 A1 = cvtpk(s[kh][8 * ct + 2], s[kh][8 * ct + 3]);
        u32 B0 = cvtpk(s[kh][8 * ct + 4], s[kh][8 * ct + 5]);
        u32 B1 = cvtpk(s[kh][8 * ct + 6], s[kh][8 * ct + 7]);
        i32x2 r0 = __builtin_amdgcn_permlane32_swap((int)A0, (int)B0, false, false);
        i32x2 r1 = __builtin_amdgcn_permlane32_swap((int)A1, (int)B1, false, false);
        u32x4 w = {(u32)r0[0], (u32)r1[0], (u32)r0[1], (u32)r1[1]};
        pf[ct] = __builtin_bit_cast(bf16x8, w);
      }
      __builtin_amdgcn_s_setprio(1);
      #pragma unroll
      for (int ct = 0; ct < 2; ++ct)
        #pragma unroll
        for (int dh = 0; dh < 2; ++dh) {
          int row = 32 * dh + lq;
          bf16x8 vf = *(const bf16x8*)(Vb + row * 64 + (((4 * kh + 2 * ct + hi) ^ (row & 7)) << 3));
          o[dh] = __builtin_amdgcn_mfma_f32_32x32x16_bf16(vf, pf[ct], o[dh], 0, 0, 0);
        }
      __builtin_amdgcn_s_setprio(0);
    }
    __syncthreads();
  }

  // ---- epilogue: y[b,t,h*64+d] = O^T[d][q] / l ----
  const int b = bh >> 4, h = bh & 15;
  float li = 1.0f / lsum;
  u16* yrow = y + (size_t)(b * T_ + qrow) * C_ + h * 64;
  #pragma unroll
  for (int dh = 0; dh < 2; ++dh)
    #pragma unroll
    for (int u = 0; u < 4; ++u) {
      ushort4 st;
      st.x = f2b(o[dh][4 * u + 0] * li);
      st.y = f2b(o[dh][4 * u + 1] * li);
      st.z = f2b(o[dh][4 * u + 2] * li);
      st.w = f2b(o[dh][4 * u + 3] * li);
      *(ushort4*)(yrow + 32 * dh + 8 * u + 4 * hi) = st;
    }
}

extern "C" void kernel_launch(void* const* d_in, const int* in_sizes, int n_in,
                              void* d_out, int out_size, void* d_ws, size_t ws_size,
                              hipStream_t stream) {
  const float* x      = (const float*)d_in[0];
  const float* W_attn = (const float*)d_in[1];
  const float* b_attn = (const float*)d_in[2];
  const float* W_proj = (const float*)d_in[3];
  const float* b_proj = (const float*)d_in[4];
  float* out = (float*)d_out;

  u16* ws = (u16*)d_ws;
  u16* xb  = ws;
  u16* Wat = xb + (size_t)M_ * C_;
  u16* Wpt = Wat + (size_t)N3_ * C_;
  u16* qkv = Wpt + (size_t)C_ * C_;
  u16* y   = qkv + (size_t)3 * QKVSZ;

  cvt_kernel<<<2048, 256, 0, stream>>>(x, xb, M_ * C_ / 4);
  tr_cvt<<<dim3(C_ / 64, N3_ / 64), 256, 0, stream>>>(W_attn, Wat, C_, N3_);
  tr_cvt<<<dim3(C_ / 64, C_ / 64), 256, 0, stream>>>(W_proj, Wpt, C_, C_);
  gemm_bt<0><<<dim3(M_ / 128, N3_ / 128), 256, 0, stream>>>(xb, Wat, b_attn, C_, N3_, qkv, nullptr);
  attn_k<<<dim3(B_ * H_, T_ / 64), 128, 0, stream>>>(qkv, qkv + QKVSZ, qkv + 2 * QKVSZ, y);
  gemm_bt<1><<<dim3(M_ / 128, C_ / 128), 256, 0, stream>>>(y, Wpt, b_proj, C_, C_, nullptr, out);
}

// Round 12
// 173.945 us; speedup vs baseline: 1.2329x; 1.0036x over previous
//
#include <hip/hip_runtime.h>
#include <hip/hip_bf16.h>

#define B_ 4
#define T_ 2048
#define C_ 1024
#define H_ 16
#define HD_ 64
#define M_ (B_*T_)        // 8192 rows
#define N3_ (3*C_)        // 3072
#define QKVSZ (B_*H_*T_*HD_)  // 8388608 elems per tensor
#define QSCALE 0.1803368801f  // 0.125 * log2(e)

typedef unsigned short u16;
typedef unsigned int u32;
typedef __attribute__((ext_vector_type(8))) __bf16 bf16x8;
typedef __attribute__((ext_vector_type(4))) float f32x4;
typedef __attribute__((ext_vector_type(16))) float f32x16;
typedef __attribute__((ext_vector_type(2))) int i32x2;
typedef __attribute__((ext_vector_type(4))) u32 u32x4;
typedef const __attribute__((address_space(1))) void* gptr_t;
typedef __attribute__((address_space(3))) void* sptr_t;

__device__ __forceinline__ u16 f2b(float f) {
  __hip_bfloat16 h = __float2bfloat16(f);
  return __builtin_bit_cast(u16, h);
}

// v_cvt_pk_bf16_f32: lo -> bits[15:0], hi -> bits[31:16]
__device__ __forceinline__ u32 cvtpk(float lo, float hi) {
  u32 r;
  asm volatile("v_cvt_pk_bf16_f32 %0, %1, %2" : "=v"(r) : "v"(lo), "v"(hi));
  return r;
}

// ---------------- fp32 -> bf16 convert (vectorized) ----------------
__global__ __launch_bounds__(256) void cvt_kernel(const float* __restrict__ src,
                                                  u16* __restrict__ dst, int n4) {
  int i = blockIdx.x * blockDim.x + threadIdx.x;
  int stride = gridDim.x * blockDim.x;
  for (; i < n4; i += stride) {
    float4 f = ((const float4*)src)[i];
    ushort4 o;
    o.x = f2b(f.x); o.y = f2b(f.y); o.z = f2b(f.z); o.w = f2b(f.w);
    ((ushort4*)dst)[i] = o;
  }
}

// ---------------- transpose + convert: src[K][N] fp32 -> dst[N][K] bf16 ----------------
__global__ __launch_bounds__(256) void tr_cvt(const float* __restrict__ src,
                                              u16* __restrict__ dst, int K, int N) {
  __shared__ u16 tile[64][72];   // +8 pad
  int k0 = blockIdx.x * 64, n0 = blockIdx.y * 64;
  #pragma unroll
  for (int t = 0; t < 16; ++t) {
    int idx = threadIdx.x + t * 256;
    int r = idx >> 6, c = idx & 63;
    tile[r][c] = f2b(src[(size_t)(k0 + r) * N + n0 + c]);
  }
  __syncthreads();
  #pragma unroll
  for (int t = 0; t < 16; ++t) {
    int idx = threadIdx.x + t * 256;
    int r = idx >> 6, c = idx & 63;       // r = local n, c = local k
    dst[(size_t)(n0 + r) * K + k0 + c] = tile[c][r];
  }
}

// ---------------- GEMM: C[M][N] = A[M][K] * Bt[N][K]^T + bias ----------------
// BM=128 x BN=128, BK=32, 4 waves (2x2), per-wave 64x64 (acc 4x4).
// 3-buffer single-barrier pipeline: stage(t+2) into buffer freed last iter;
// 8 frag ds_reads -> lgkmcnt(0) -> MFMA -> counted vmcnt(4) -> ONE s_barrier.
// Granule-XOR swizzle via pre-swizzled global source + swizzled ds_read.
// EPI 0: scatter to q (scaled) / k / v^T.  EPI 1: fp32 out [M][N].
template <int EPI>
__global__ __launch_bounds__(256, 3) void gemm_bt(const u16* __restrict__ A,
                                                  const u16* __restrict__ Bt,
                                                  const float* __restrict__ bias,
                                                  int K, int N,
                                                  u16* __restrict__ out_qkv,
                                                  float* __restrict__ out_f) {
  __shared__ __align__(16) u16 As[3][128 * 32];
  __shared__ __align__(16) u16 Bs[3][128 * 32];
  const int tid = threadIdx.x;
  const int wave = tid >> 6, lane = tid & 63;
  const int lr = lane & 15, lk = lane >> 4;

  const int m0 = blockIdx.x * 128, n0 = blockIdx.y * 128;
  const int wr = (wave >> 1) * 64, wc = (wave & 1) * 64;

  f32x4 acc[4][4] = {};

  auto stage = [&](int buf, int it) {            // 4 gloads/thread (2 A + 2 B)
    const int kt = it * 32;
    #pragma unroll
    for (int i = 0; i < 2; ++i) {
      int ch = i * 256 + tid;                    // A: 512 chunks
      int row = ch >> 2;
      int gsrc = (ch & 3) ^ ((row >> 1) & 3);
      __builtin_amdgcn_global_load_lds((gptr_t)(A + (size_t)(m0 + row) * K + kt + gsrc * 8),
                                       (sptr_t)(&As[buf][ch * 8]), 16, 0, 0);
    }
    #pragma unroll
    for (int i = 0; i < 2; ++i) {
      int ch = i * 256 + tid;                    // B: 512 chunks
      int row = ch >> 2;
      int gsrc = (ch & 3) ^ ((row >> 1) & 3);
      __builtin_amdgcn_global_load_lds((gptr_t)(Bt + (size_t)(n0 + row) * K + kt + gsrc * 8),
                                       (sptr_t)(&Bs[buf][ch * 8]), 16, 0, 0);
    }
  };

  const int KI = K / 32;                         // 32 iters (K=1024)
  stage(0, 0);
  stage(1, 1);
  asm volatile("s_waitcnt vmcnt(4)" ::: "memory");   // tile 0 complete
  __builtin_amdgcn_s_barrier();

  for (int it = 0; it < KI; ++it) {
    const int cur = it % 3;
    const bool pre = (it + 2 < KI);
    if (pre) stage((it + 2) % 3, it + 2);        // into buffer freed last iter

    // ---- read all frags of tile t (8 ds_read_b128) ----
    bf16x8 af[4], bfr[4];
    #pragma unroll
    for (int mi = 0; mi < 4; ++mi) {
      int r = wr + mi * 16 + lr;
      af[mi] = *(const bf16x8*)(&As[cur][r * 32 + ((lk ^ ((r >> 1) & 3)) << 3)]);
    }
    #pragma unroll
    for (int ni = 0; ni < 4; ++ni) {
      int r = wc + ni * 16 + lr;
      bfr[ni] = *(const bf16x8*)(&Bs[cur][r * 32 + ((lk ^ ((r >> 1) & 3)) << 3)]);
    }
    asm volatile("s_waitcnt lgkmcnt(0)" ::: "memory");
    __builtin_amdgcn_sched_barrier(0);

    __builtin_amdgcn_s_setprio(1);
    #pragma unroll
    for (int mi = 0; mi < 4; ++mi)
      #pragma unroll
      for (int ni = 0; ni < 4; ++ni)
        acc[mi][ni] = __builtin_amdgcn_mfma_f32_16x16x32_bf16(af[mi], bfr[ni], acc[mi][ni], 0, 0, 0);
    __builtin_amdgcn_s_setprio(0);

    // ---- tile boundary: counted wait (t+1 landed, t+2 in flight) ----
    if (pre) asm volatile("s_waitcnt vmcnt(4)" ::: "memory");
    else     asm volatile("s_waitcnt vmcnt(0)" ::: "memory");
    __builtin_amdgcn_s_barrier();
  }

  if (EPI == 0) {
    const int sel = (n0 >> 10);                   // whole block same q/k/v segment
    #pragma unroll
    for (int mi = 0; mi < 4; ++mi) {
      #pragma unroll
      for (int ni = 0; ni < 4; ++ni) {
        int m = m0 + wr + mi * 16 + lk * 4;       // +j
        int n = n0 + wc + ni * 16 + lr;
        int rem = n & 1023, h = rem >> 6, d = rem & 63;
        int b = m >> 11, t = m & 2047;
        if (sel == 2) {                           // v^T: t contiguous -> ushort4
          ushort4 st;
          #pragma unroll
          for (int j = 0; j < 4; ++j)
            ((u16*)&st)[j] = f2b(acc[mi][ni][j] + bias[n]);
          *(ushort4*)(out_qkv + 2 * (size_t)QKVSZ +
                      (((size_t)(b * H_ + h) * HD_ + d) * T_ + t)) = st;
        } else {
          #pragma unroll
          for (int j = 0; j < 4; ++j) {
            float val = acc[mi][ni][j] + bias[n];
            if (sel == 0) val *= QSCALE;
            out_qkv[(size_t)sel * QKVSZ +
                    (((size_t)(b * H_ + h) * T_ + (t + j)) * HD_ + d)] = f2b(val);
          }
        }
      }
    }
  } else {
    #pragma unroll
    for (int mi = 0; mi < 4; ++mi)
      #pragma unroll
      for (int ni = 0; ni < 4; ++ni)
        #pragma unroll
        for (int j = 0; j < 4; ++j) {
          int m = m0 + wr + mi * 16 + lk * 4 + j;
          int n = n0 + wc + ni * 16 + lr;
          out_f[(size_t)m * C_ + n] = acc[mi][ni][j] + bias[n];
        }
  }
}

// ---------------- causal flash attention ----------------
// 256 threads = 4 waves; q-tile 128 (wave w owns q-rows [BQ+32w, BQ+32w+32)).
// grid (bh=64, 16 q-tiles) = 1024 blocks, heavy-first -> 4 blocks/CU ALL
// resident (LDS caps 5) = 16 waves/CU: one wave's softmax VALU overlaps
// other waves' MFMA/LDS. K/V staged once per block serves 4 waves (2x less
// stage traffic per q than 2-wave blocks). 32x32x16 MFMAs, swapped
// S^T = mfma(K,Q). Softmax per-lane: raw v_exp_f32, shfl_xor(32) reduce.
// P in registers via cvt_pk + permlane32_swap. O^T = mfma(Vt, P).
// Granule swizzle (row&7)^((row>>3)&3) applied on BOTH sides.
// Wave w: active while kt <= 2qtb+(w>>1); diag tile kt == 2qtb+(w>>1);
// even w: kh1 fully masked (skip), kh0 diagonal; odd w: kh0 full, kh1 diag.
__global__ __launch_bounds__(256, 4) void attn_k(const u16* __restrict__ q,
                                                 const u16* __restrict__ k,
                                                 const u16* __restrict__ vt,
                                                 u16* __restrict__ y) {
  __shared__ __align__(16) u16 Ks[2][64 * 64];
  __shared__ __align__(16) u16 Vs[2][64 * 64];
  const int tid = threadIdx.x;
  const int wave = tid >> 6, lane = tid & 63;
  const int hi = lane >> 5, lq = lane & 31;
  const int qtb = gridDim.y - 1 - blockIdx.y;    // 15..0, heavy first
  const int bh = blockIdx.x;                     // fastest dim -> XCD spread
  const size_t koff = (size_t)bh * T_ * HD_;     // q,k: [bh][t][d]
  const size_t voff = (size_t)bh * HD_ * T_;     // vt:  [bh][d][t]
  const int qrow = qtb * 128 + 32 * wave + lq;   // this lane's q row (global)
  const int sw = (lq & 7) ^ ((lq >> 3) & 3);     // read-granule swizzle (row=32kh+lq)

  // Q B-frags (pre-scaled by 0.125*log2e): qf[c] = Q[qrow][16c+8hi .. +8]
  bf16x8 qf[4];
  #pragma unroll
  for (int c = 0; c < 4; ++c)
    qf[c] = *(const bf16x8*)(q + koff + (size_t)qrow * HD_ + 16 * c + 8 * hi);

  f32x16 o[2] = {};                              // [dh]: O^T rows 32dh..
  float mrun = -1e30f, lsum = 0.f;

  auto stage = [&](int buf, int kt) {
    const u16* kb = k + koff + (size_t)kt * 64 * HD_;
    const u16* vb = vt + voff + (size_t)kt * 64;
    #pragma unroll
    for (int j = 0; j < 2; ++j) {
      int cb = j * 256 + wave * 64;              // wave-uniform chunk base
      int ch = cb + lane;
      int row = ch >> 3, gg = ch & 7;
      int src = gg ^ (row & 7) ^ ((row >> 3) & 3);   // pre-swizzled source
      __builtin_amdgcn_global_load_lds((gptr_t)(kb + row * HD_ + src * 8),
                                       (sptr_t)(&Ks[buf][cb * 8]), 16, 0, 0);
      __builtin_amdgcn_global_load_lds((gptr_t)(vb + (size_t)row * T_ + src * 8),
                                       (sptr_t)(&Vs[buf][cb * 8]), 16, 0, 0);
    }
  };

  const int nt = 2 * qtb + 2;
  stage(0, 0);
  __syncthreads();

  for (int kt = 0; kt < nt; ++kt) {
    const int cur = kt & 1;
    if (kt + 1 < nt) stage(cur ^ 1, kt + 1);
    const bool active = (kt <= 2 * qtb + (wave >> 1));
    if (active) {
      const bool dia = (kt == 2 * qtb + (wave >> 1));
      const bool skip1 = dia && ((wave & 1) == 0);   // kh=1 fully masked
      const u16* Kb = &Ks[cur][0];
      const u16* Vb = &Vs[cur][0];

      // ---- S^T = K Q^T ----
      f32x16 s[2] = {};
      __builtin_amdgcn_s_setprio(1);
      #pragma unroll
      for (int c = 0; c < 4; ++c) {
        #pragma unroll
        for (int kh = 0; kh < 2; ++kh) {
          if (kh == 1 && skip1) continue;
          int row = 32 * kh + lq;
          bf16x8 kf = *(const bf16x8*)(Kb + row * 64 + (((2 * c + hi) ^ sw) << 3));
          s[kh] = __builtin_amdgcn_mfma_f32_32x32x16_bf16(kf, qf[c], s[kh], 0, 0, 0);
        }
      }
      __builtin_amdgcn_s_setprio(0);

      if (dia) {
        #pragma unroll
        for (int rr = 0; rr < 16; ++rr) {
          int kg = 64 * kt + 4 * hi + (rr & 3) + 8 * (rr >> 2);
          if ((wave & 1) == 0) { if (kg > qrow)      s[0][rr] = -1e30f; }
          else                 { if (kg + 32 > qrow) s[1][rr] = -1e30f; }
        }
      }

      // ---- online softmax (lane and lane^32 share a q-row) ----
      float g0, g1, g2, g3;
      {
        const f32x16& a = s[0];
        g0 = fmaxf(fmaxf(a[0], a[1]),   fmaxf(a[2], a[3]));
        g1 = fmaxf(fmaxf(a[4], a[5]),   fmaxf(a[6], a[7]));
        g2 = fmaxf(fmaxf(a[8], a[9]),   fmaxf(a[10], a[11]));
        g3 = fmaxf(fmaxf(a[12], a[13]), fmaxf(a[14], a[15]));
      }
      if (!skip1) {
        const f32x16& a = s[1];
        g0 = fmaxf(g0, fmaxf(fmaxf(a[0], a[1]),   fmaxf(a[2], a[3])));
        g1 = fmaxf(g1, fmaxf(fmaxf(a[4], a[5]),   fmaxf(a[6], a[7])));
        g2 = fmaxf(g2, fmaxf(fmaxf(a[8], a[9]),   fmaxf(a[10], a[11])));
        g3 = fmaxf(g3, fmaxf(fmaxf(a[12], a[13]), fmaxf(a[14], a[15])));
      }
      float tm = fmaxf(fmaxf(g0, g1), fmaxf(g2, g3));
      tm = fmaxf(tm, __shfl_xor(tm, 32));
      if (__any(tm > mrun + 8.f)) {              // defer-max (T13)
        float mn = fmaxf(mrun, tm);
        float al = __builtin_amdgcn_exp2f(mrun - mn);
        lsum *= al;
        o[0] *= al;
        o[1] *= al;
        mrun = mn;
      }
      float rs = 0.f;
      #pragma unroll
      for (int kh = 0; kh < 2; ++kh) {
        if (kh == 1 && skip1) continue;
        #pragma unroll
        for (int rr = 0; rr < 16; ++rr) {
          float p = __builtin_amdgcn_exp2f(s[kh][rr] - mrun);
          s[kh][rr] = p;
          rs += p;
        }
      }
      rs += __shfl_xor(rs, 32);
      lsum += rs;

      // ---- PV: O^T[d][q] += Vt P (P assembled in-register) ----
      #pragma unroll
      for (int kh = 0; kh < 2; ++kh) {
        if (kh == 1 && skip1) continue;
        bf16x8 pf[2];
        #pragma unroll
        for (int ct = 0; ct < 2; ++ct) {
          u32 A0 = cvtpk(s[kh][8 * ct + 0], s[kh][8 * ct + 1]);
          u32 A1 = cvtpk(s[kh][8 * ct + 2], s[kh][8 * ct + 3]);
          u32 B0 = cvtpk(s[kh][8 * ct + 4], s[kh][8 * ct + 5]);
          u32 B1 = cvtpk(s[kh][8 * ct + 6], s[kh][8 * ct + 7]);
          i32x2 r0 = __builtin_amdgcn_permlane32_swap((int)A0, (int)B0, false, false);
          i32x2 r1 = __builtin_amdgcn_permlane32_swap((int)A1, (int)B1, false, false);
          u32x4 w = {(u32)r0[0], (u32)r1[0], (u32)r0[1], (u32)r1[1]};
          pf[ct] = __builtin_bit_cast(bf16x8, w);
        }
        __builtin_amdgcn_s_setprio(1);
        #pragma unroll
        for (int ct = 0; ct < 2; ++ct)
          #pragma unroll
          for (int dh = 0; dh < 2; ++dh) {
            int row = 32 * dh + lq;
            bf16x8 vf = *(const bf16x8*)(Vb + row * 64 + (((4 * kh + 2 * ct + hi) ^ sw) << 3));
            o[dh] = __builtin_amdgcn_mfma_f32_32x32x16_bf16(vf, pf[ct], o[dh], 0, 0, 0);
          }
        __builtin_amdgcn_s_setprio(0);
      }
    }
    __syncthreads();
  }

  // ---- epilogue: y[b,t,h*64+d] = O^T[d][q] / l ----
  const int b = bh >> 4, h = bh & 15;
  float li = 1.0f / lsum;
  u16* yrow = y + (size_t)(b * T_ + qrow) * C_ + h * 64;
  #pragma unroll
  for (int dh = 0; dh < 2; ++dh)
    #pragma unroll
    for (int u = 0; u < 4; ++u) {
      ushort4 st;
      st.x = f2b(o[dh][4 * u + 0] * li);
      st.y = f2b(o[dh][4 * u + 1] * li);
      st.z = f2b(o[dh][4 * u + 2] * li);
      st.w = f2b(o[dh][4 * u + 3] * li);
      *(ushort4*)(yrow + 32 * dh + 8 * u + 4 * hi) = st;
    }
}

extern "C" void kernel_launch(void* const* d_in, const int* in_sizes, int n_in,
                              void* d_out, int out_size, void* d_ws, size_t ws_size,
                              hipStream_t stream) {
  const float* x      = (const float*)d_in[0];
  const float* W_attn = (const float*)d_in[1];
  const float* b_attn = (const float*)d_in[2];
  const float* W_proj = (const float*)d_in[3];
  const float* b_proj = (const float*)d_in[4];
  float* out = (float*)d_out;

  u16* ws = (u16*)d_ws;
  u16* xb  = ws;
  u16* Wat = xb + (size_t)M_ * C_;
  u16* Wpt = Wat + (size_t)N3_ * C_;
  u16* qkv = Wpt + (size_t)C_ * C_;
  u16* y   = qkv + (size_t)3 * QKVSZ;

  cvt_kernel<<<2048, 256, 0, stream>>>(x, xb, M_ * C_ / 4);
  tr_cvt<<<dim3(C_ / 64, N3_ / 64), 256, 0, stream>>>(W_attn, Wat, C_, N3_);
  tr_cvt<<<dim3(C_ / 64, C_ / 64), 256, 0, stream>>>(W_proj, Wpt, C_, C_);
  gemm_bt<0><<<dim3(M_ / 128, N3_ / 128), 256, 0, stream>>>(xb, Wat, b_attn, C_, N3_, qkv, nullptr);
  attn_k<<<dim3(B_ * H_, T_ / 128), 256, 0, stream>>>(qkv, qkv + QKVSZ, qkv + 2 * QKVSZ, y);
  gemm_bt<1><<<dim3(M_ / 128, C_ / 128), 256, 0, stream>>>(y, Wpt, b_proj, C_, C_, nullptr, out);
}

// Round 13
// 171.631 us; speedup vs baseline: 1.2495x; 1.0135x over previous
//
#include <hip/hip_runtime.h>
#include <hip/hip_bf16.h>

#define B_ 4
#define T_ 2048
#define C_ 1024
#define H_ 16
#define HD_ 64
#define M_ (B_*T_)        // 8192 rows
#define N3_ (3*C_)        // 3072
#define QKVSZ (B_*H_*T_*HD_)  // 8388608 elems per tensor
#define QSCALE 0.1803368801f  // 0.125 * log2(e)

typedef unsigned short u16;
typedef unsigned int u32;
typedef __attribute__((ext_vector_type(8))) __bf16 bf16x8;
typedef __attribute__((ext_vector_type(4))) float f32x4;
typedef __attribute__((ext_vector_type(16))) float f32x16;
typedef __attribute__((ext_vector_type(2))) int i32x2;
typedef __attribute__((ext_vector_type(4))) u32 u32x4;
typedef const __attribute__((address_space(1))) void* gptr_t;
typedef __attribute__((address_space(3))) void* sptr_t;

__device__ __forceinline__ u16 f2b(float f) {
  __hip_bfloat16 h = __float2bfloat16(f);
  return __builtin_bit_cast(u16, h);
}

// v_cvt_pk_bf16_f32: lo -> bits[15:0], hi -> bits[31:16]
__device__ __forceinline__ u32 cvtpk(float lo, float hi) {
  u32 r;
  asm volatile("v_cvt_pk_bf16_f32 %0, %1, %2" : "=v"(r) : "v"(lo), "v"(hi));
  return r;
}

// ---------------- fp32 -> bf16 convert (vectorized) ----------------
__global__ __launch_bounds__(256) void cvt_kernel(const float* __restrict__ src,
                                                  u16* __restrict__ dst, int n4) {
  int i = blockIdx.x * blockDim.x + threadIdx.x;
  int stride = gridDim.x * blockDim.x;
  for (; i < n4; i += stride) {
    float4 f = ((const float4*)src)[i];
    ushort4 o;
    o.x = f2b(f.x); o.y = f2b(f.y); o.z = f2b(f.z); o.w = f2b(f.w);
    ((ushort4*)dst)[i] = o;
  }
}

// ---------------- transpose + convert both weights (merged) ----------------
// y < 48: W_attn[1024][3072] -> Wat[3072][1024];  y >= 48: W_proj -> Wpt.
__global__ __launch_bounds__(256) void tr_cvt2(const float* __restrict__ Wa,
                                               u16* __restrict__ Wat,
                                               const float* __restrict__ Wp,
                                               u16* __restrict__ Wpt) {
  __shared__ u16 tile[64][72];   // +8 pad
  const bool attn = (blockIdx.y < 48);
  const float* src = attn ? Wa : Wp;
  u16* dst = attn ? Wat : Wpt;
  const int N = attn ? N3_ : C_;
  int k0 = blockIdx.x * 64, n0 = (attn ? blockIdx.y : blockIdx.y - 48) * 64;
  #pragma unroll
  for (int t = 0; t < 16; ++t) {
    int idx = threadIdx.x + t * 256;
    int r = idx >> 6, c = idx & 63;
    tile[r][c] = f2b(src[(size_t)(k0 + r) * N + n0 + c]);
  }
  __syncthreads();
  #pragma unroll
  for (int t = 0; t < 16; ++t) {
    int idx = threadIdx.x + t * 256;
    int r = idx >> 6, c = idx & 63;       // r = local n, c = local k
    dst[(size_t)(n0 + r) * C_ + k0 + c] = tile[c][r];
  }
}

// ---------------- GEMM: C[M][N] = A[M][K] * Bt[N][K]^T + bias ----------------
// BM=128 x BN=128, BK=32, 4 waves (2x2), per-wave 64x64 (acc 4x4).
// 3-buffer single-barrier pipeline: stage(t+2) into buffer freed last iter;
// 8 frag ds_reads -> MFMA (compiler-scheduled fine-grained lgkmcnt: NO
// explicit lgkmcnt(0)/sched_barrier pin — plain-C++ ds_reads are dependency-
// tracked, and in-order MFMA issue still forces read-completion before the
// end barrier, keeping mod-3 buffer reuse safe) -> counted vmcnt(4) ->
// ONE s_barrier. Granule-XOR swizzle via pre-swizzled global source.
// EPI 0: scatter to q (scaled) / k / v^T.  EPI 1: fp32 out [M][N].
template <int EPI>
__global__ __launch_bounds__(256, 3) void gemm_bt(const u16* __restrict__ A,
                                                  const u16* __restrict__ Bt,
                                                  const float* __restrict__ bias,
                                                  int K, int N,
                                                  u16* __restrict__ out_qkv,
                                                  float* __restrict__ out_f) {
  __shared__ __align__(16) u16 As[3][128 * 32];
  __shared__ __align__(16) u16 Bs[3][128 * 32];
  const int tid = threadIdx.x;
  const int wave = tid >> 6, lane = tid & 63;
  const int lr = lane & 15, lk = lane >> 4;

  const int m0 = blockIdx.x * 128, n0 = blockIdx.y * 128;
  const int wr = (wave >> 1) * 64, wc = (wave & 1) * 64;

  f32x4 acc[4][4] = {};

  auto stage = [&](int buf, int it) {            // 4 gloads/thread (2 A + 2 B)
    const int kt = it * 32;
    #pragma unroll
    for (int i = 0; i < 2; ++i) {
      int ch = i * 256 + tid;                    // A: 512 chunks
      int row = ch >> 2;
      int gsrc = (ch & 3) ^ ((row >> 1) & 3);
      __builtin_amdgcn_global_load_lds((gptr_t)(A + (size_t)(m0 + row) * K + kt + gsrc * 8),
                                       (sptr_t)(&As[buf][ch * 8]), 16, 0, 0);
    }
    #pragma unroll
    for (int i = 0; i < 2; ++i) {
      int ch = i * 256 + tid;                    // B: 512 chunks
      int row = ch >> 2;
      int gsrc = (ch & 3) ^ ((row >> 1) & 3);
      __builtin_amdgcn_global_load_lds((gptr_t)(Bt + (size_t)(n0 + row) * K + kt + gsrc * 8),
                                       (sptr_t)(&Bs[buf][ch * 8]), 16, 0, 0);
    }
  };

  const int KI = K / 32;                         // 32 iters (K=1024)
  stage(0, 0);
  stage(1, 1);
  asm volatile("s_waitcnt vmcnt(4)" ::: "memory");   // tile 0 complete
  __builtin_amdgcn_s_barrier();

  for (int it = 0; it < KI; ++it) {
    const int cur = it % 3;
    const bool pre = (it + 2 < KI);
    if (pre) stage((it + 2) % 3, it + 2);        // into buffer freed last iter

    // ---- read frags of tile t; compiler interleaves reads with MFMAs ----
    bf16x8 af[4], bfr[4];
    #pragma unroll
    for (int mi = 0; mi < 4; ++mi) {
      int r = wr + mi * 16 + lr;
      af[mi] = *(const bf16x8*)(&As[cur][r * 32 + ((lk ^ ((r >> 1) & 3)) << 3)]);
    }
    #pragma unroll
    for (int ni = 0; ni < 4; ++ni) {
      int r = wc + ni * 16 + lr;
      bfr[ni] = *(const bf16x8*)(&Bs[cur][r * 32 + ((lk ^ ((r >> 1) & 3)) << 3)]);
    }

    __builtin_amdgcn_s_setprio(1);
    #pragma unroll
    for (int mi = 0; mi < 4; ++mi)
      #pragma unroll
      for (int ni = 0; ni < 4; ++ni)
        acc[mi][ni] = __builtin_amdgcn_mfma_f32_16x16x32_bf16(af[mi], bfr[ni], acc[mi][ni], 0, 0, 0);
    __builtin_amdgcn_s_setprio(0);

    // ---- tile boundary: counted wait (t+1 landed, t+2 in flight) ----
    if (pre) asm volatile("s_waitcnt vmcnt(4)" ::: "memory");
    else     asm volatile("s_waitcnt vmcnt(0)" ::: "memory");
    __builtin_amdgcn_s_barrier();
  }

  if (EPI == 0) {
    const int sel = (n0 >> 10);                   // whole block same q/k/v segment
    #pragma unroll
    for (int mi = 0; mi < 4; ++mi) {
      #pragma unroll
      for (int ni = 0; ni < 4; ++ni) {
        int m = m0 + wr + mi * 16 + lk * 4;       // +j
        int n = n0 + wc + ni * 16 + lr;
        int rem = n & 1023, h = rem >> 6, d = rem & 63;
        int b = m >> 11, t = m & 2047;
        if (sel == 2) {                           // v^T: t contiguous -> ushort4
          ushort4 st;
          #pragma unroll
          for (int j = 0; j < 4; ++j)
            ((u16*)&st)[j] = f2b(acc[mi][ni][j] + bias[n]);
          *(ushort4*)(out_qkv + 2 * (size_t)QKVSZ +
                      (((size_t)(b * H_ + h) * HD_ + d) * T_ + t)) = st;
        } else {
          #pragma unroll
          for (int j = 0; j < 4; ++j) {
            float val = acc[mi][ni][j] + bias[n];
            if (sel == 0) val *= QSCALE;
            out_qkv[(size_t)sel * QKVSZ +
                    (((size_t)(b * H_ + h) * T_ + (t + j)) * HD_ + d)] = f2b(val);
          }
        }
      }
    }
  } else {
    #pragma unroll
    for (int mi = 0; mi < 4; ++mi)
      #pragma unroll
      for (int ni = 0; ni < 4; ++ni)
        #pragma unroll
        for (int j = 0; j < 4; ++j) {
          int m = m0 + wr + mi * 16 + lk * 4 + j;
          int n = n0 + wc + ni * 16 + lr;
          out_f[(size_t)m * C_ + n] = acc[mi][ni][j] + bias[n];
        }
  }
}

// ---------------- causal flash attention ----------------
// 256 threads = 4 waves; q-tile 128 (wave w owns q-rows [BQ+32w, BQ+32w+32)).
// grid (bh=64, 16 q-tiles) = 1024 blocks, heavy-first -> 4 blocks/CU ALL
// resident = 16 waves/CU. K/V staged once per block serves 4 waves.
// 32x32x16 MFMAs, swapped S^T = mfma(K,Q). Softmax per-lane: raw v_exp_f32,
// shfl_xor(32) reduce. P in registers via cvt_pk + permlane32_swap.
// O^T = mfma(Vt, P). Granule swizzle (row&7)^((row>>3)&3) on BOTH sides.
__global__ __launch_bounds__(256, 4) void attn_k(const u16* __restrict__ q,
                                                 const u16* __restrict__ k,
                                                 const u16* __restrict__ vt,
                                                 u16* __restrict__ y) {
  __shared__ __align__(16) u16 Ks[2][64 * 64];
  __shared__ __align__(16) u16 Vs[2][64 * 64];
  const int tid = threadIdx.x;
  const int wave = tid >> 6, lane = tid & 63;
  const int hi = lane >> 5, lq = lane & 31;
  const int qtb = gridDim.y - 1 - blockIdx.y;    // 15..0, heavy first
  const int bh = blockIdx.x;                     // fastest dim -> XCD spread
  const size_t koff = (size_t)bh * T_ * HD_;     // q,k: [bh][t][d]
  const size_t voff = (size_t)bh * HD_ * T_;     // vt:  [bh][d][t]
  const int qrow = qtb * 128 + 32 * wave + lq;   // this lane's q row (global)
  const int sw = (lq & 7) ^ ((lq >> 3) & 3);     // read-granule swizzle (row=32kh+lq)

  // Q B-frags (pre-scaled by 0.125*log2e): qf[c] = Q[qrow][16c+8hi .. +8]
  bf16x8 qf[4];
  #pragma unroll
  for (int c = 0; c < 4; ++c)
    qf[c] = *(const bf16x8*)(q + koff + (size_t)qrow * HD_ + 16 * c + 8 * hi);

  f32x16 o[2] = {};                              // [dh]: O^T rows 32dh..
  float mrun = -1e30f, lsum = 0.f;

  auto stage = [&](int buf, int kt) {
    const u16* kb = k + koff + (size_t)kt * 64 * HD_;
    const u16* vb = vt + voff + (size_t)kt * 64;
    #pragma unroll
    for (int j = 0; j < 2; ++j) {
      int cb = j * 256 + wave * 64;              // wave-uniform chunk base
      int ch = cb + lane;
      int row = ch >> 3, gg = ch & 7;
      int src = gg ^ (row & 7) ^ ((row >> 3) & 3);   // pre-swizzled source
      __builtin_amdgcn_global_load_lds((gptr_t)(kb + row * HD_ + src * 8),
                                       (sptr_t)(&Ks[buf][cb * 8]), 16, 0, 0);
      __builtin_amdgcn_global_load_lds((gptr_t)(vb + (size_t)row * T_ + src * 8),
                                       (sptr_t)(&Vs[buf][cb * 8]), 16, 0, 0);
    }
  };

  const int nt = 2 * qtb + 2;
  stage(0, 0);
  __syncthreads();

  for (int kt = 0; kt < nt; ++kt) {
    const int cur = kt & 1;
    if (kt + 1 < nt) stage(cur ^ 1, kt + 1);
    const bool active = (kt <= 2 * qtb + (wave >> 1));
    if (active) {
      const bool dia = (kt == 2 * qtb + (wave >> 1));
      const bool skip1 = dia && ((wave & 1) == 0);   // kh=1 fully masked
      const u16* Kb = &Ks[cur][0];
      const u16* Vb = &Vs[cur][0];

      // ---- S^T = K Q^T ----
      f32x16 s[2] = {};
      __builtin_amdgcn_s_setprio(1);
      #pragma unroll
      for (int c = 0; c < 4; ++c) {
        #pragma unroll
        for (int kh = 0; kh < 2; ++kh) {
          if (kh == 1 && skip1) continue;
          int row = 32 * kh + lq;
          bf16x8 kf = *(const bf16x8*)(Kb + row * 64 + (((2 * c + hi) ^ sw) << 3));
          s[kh] = __builtin_amdgcn_mfma_f32_32x32x16_bf16(kf, qf[c], s[kh], 0, 0, 0);
        }
      }
      __builtin_amdgcn_s_setprio(0);

      if (dia) {
        #pragma unroll
        for (int rr = 0; rr < 16; ++rr) {
          int kg = 64 * kt + 4 * hi + (rr & 3) + 8 * (rr >> 2);
          if ((wave & 1) == 0) { if (kg > qrow)      s[0][rr] = -1e30f; }
          else                 { if (kg + 32 > qrow) s[1][rr] = -1e30f; }
        }
      }

      // ---- online softmax (lane and lane^32 share a q-row) ----
      float g0, g1, g2, g3;
      {
        const f32x16& a = s[0];
        g0 = fmaxf(fmaxf(a[0], a[1]),   fmaxf(a[2], a[3]));
        g1 = fmaxf(fmaxf(a[4], a[5]),   fmaxf(a[6], a[7]));
        g2 = fmaxf(fmaxf(a[8], a[9]),   fmaxf(a[10], a[11]));
        g3 = fmaxf(fmaxf(a[12], a[13]), fmaxf(a[14], a[15]));
      }
      if (!skip1) {
        const f32x16& a = s[1];
        g0 = fmaxf(g0, fmaxf(fmaxf(a[0], a[1]),   fmaxf(a[2], a[3])));
        g1 = fmaxf(g1, fmaxf(fmaxf(a[4], a[5]),   fmaxf(a[6], a[7])));
        g2 = fmaxf(g2, fmaxf(fmaxf(a[8], a[9]),   fmaxf(a[10], a[11])));
        g3 = fmaxf(g3, fmaxf(fmaxf(a[12], a[13]), fmaxf(a[14], a[15])));
      }
      float tm = fmaxf(fmaxf(g0, g1), fmaxf(g2, g3));
      tm = fmaxf(tm, __shfl_xor(tm, 32));
      if (__any(tm > mrun + 8.f)) {              // defer-max (T13)
        float mn = fmaxf(mrun, tm);
        float al = __builtin_amdgcn_exp2f(mrun - mn);
        lsum *= al;
        o[0] *= al;
        o[1] *= al;
        mrun = mn;
      }
      float rs = 0.f;
      #pragma unroll
      for (int kh = 0; kh < 2; ++kh) {
        if (kh == 1 && skip1) continue;
        #pragma unroll
        for (int rr = 0; rr < 16; ++rr) {
          float p = __builtin_amdgcn_exp2f(s[kh][rr] - mrun);
          s[kh][rr] = p;
          rs += p;
        }
      }
      rs += __shfl_xor(rs, 32);
      lsum += rs;

      // ---- PV: O^T[d][q] += Vt P (P assembled in-register) ----
      #pragma unroll
      for (int kh = 0; kh < 2; ++kh) {
        if (kh == 1 && skip1) continue;
        bf16x8 pf[2];
        #pragma unroll
        for (int ct = 0; ct < 2; ++ct) {
          u32 A0 = cvtpk(s[kh][8 * ct + 0], s[kh][8 * ct + 1]);
          u32 A1 = cvtpk(s[kh][8 * ct + 2], s[kh][8 * ct + 3]);
          u32 B0 = cvtpk(s[kh][8 * ct + 4], s[kh][8 * ct + 5]);
          u32 B1 = cvtpk(s[kh][8 * ct + 6], s[kh][8 * ct + 7]);
          i32x2 r0 = __builtin_amdgcn_permlane32_swap((int)A0, (int)B0, false, false);
          i32x2 r1 = __builtin_amdgcn_permlane32_swap((int)A1, (int)B1, false, false);
          u32x4 w = {(u32)r0[0], (u32)r1[0], (u32)r0[1], (u32)r1[1]};
          pf[ct] = __builtin_bit_cast(bf16x8, w);
        }
        __builtin_amdgcn_s_setprio(1);
        #pragma unroll
        for (int ct = 0; ct < 2; ++ct)
          #pragma unroll
          for (int dh = 0; dh < 2; ++dh) {
            int row = 32 * dh + lq;
            bf16x8 vf = *(const bf16x8*)(Vb + row * 64 + (((4 * kh + 2 * ct + hi) ^ sw) << 3));
            o[dh] = __builtin_amdgcn_mfma_f32_32x32x16_bf16(vf, pf[ct], o[dh], 0, 0, 0);
          }
        __builtin_amdgcn_s_setprio(0);
      }
    }
    __syncthreads();
  }

  // ---- epilogue: y[b,t,h*64+d] = O^T[d][q] / l ----
  const int b = bh >> 4, h = bh & 15;
  float li = 1.0f / lsum;
  u16* yrow = y + (size_t)(b * T_ + qrow) * C_ + h * 64;
  #pragma unroll
  for (int dh = 0; dh < 2; ++dh)
    #pragma unroll
    for (int u = 0; u < 4; ++u) {
      ushort4 st;
      st.x = f2b(o[dh][4 * u + 0] * li);
      st.y = f2b(o[dh][4 * u + 1] * li);
      st.z = f2b(o[dh][4 * u + 2] * li);
      st.w = f2b(o[dh][4 * u + 3] * li);
      *(ushort4*)(yrow + 32 * dh + 8 * u + 4 * hi) = st;
    }
}

extern "C" void kernel_launch(void* const* d_in, const int* in_sizes, int n_in,
                              void* d_out, int out_size, void* d_ws, size_t ws_size,
                              hipStream_t stream) {
  const float* x      = (const float*)d_in[0];
  const float* W_attn = (const float*)d_in[1];
  const float* b_attn = (const float*)d_in[2];
  const float* W_proj = (const float*)d_in[3];
  const float* b_proj = (const float*)d_in[4];
  float* out = (float*)d_out;

  u16* ws = (u16*)d_ws;
  u16* xb  = ws;
  u16* Wat = xb + (size_t)M_ * C_;
  u16* Wpt = Wat + (size_t)N3_ * C_;
  u16* qkv = Wpt + (size_t)C_ * C_;
  u16* y   = qkv + (size_t)3 * QKVSZ;

  cvt_kernel<<<2048, 256, 0, stream>>>(x, xb, M_ * C_ / 4);
  tr_cvt2<<<dim3(C_ / 64, 64), 256, 0, stream>>>(W_attn, Wat, W_proj, Wpt);
  gemm_bt<0><<<dim3(M_ / 128, N3_ / 128), 256, 0, stream>>>(xb, Wat, b_attn, C_, N3_, qkv, nullptr);
  attn_k<<<dim3(B_ * H_, T_ / 128), 256, 0, stream>>>(qkv, qkv + QKVSZ, qkv + 2 * QKVSZ, y);
  gemm_bt<1><<<dim3(M_ / 128, C_ / 128), 256, 0, stream>>>(y, Wpt, b_proj, C_, C_, nullptr, out);
}

// Round 14
// 166.438 us; speedup vs baseline: 1.2885x; 1.0312x over previous
//
#include <hip/hip_runtime.h>
#include <hip/hip_bf16.h>

#define B_ 4
#define T_ 2048
#define C_ 1024
#define H_ 16
#define HD_ 64
#define M_ (B_*T_)        // 8192 rows
#define N3_ (3*C_)        // 3072
#define QKVSZ (B_*H_*T_*HD_)  // 8388608 elems per tensor
#define QSCALE 0.1803368801f  // 0.125 * log2(e)

typedef unsigned short u16;
typedef unsigned int u32;
typedef __attribute__((ext_vector_type(8))) __bf16 bf16x8;
typedef __attribute__((ext_vector_type(4))) float f32x4;
typedef __attribute__((ext_vector_type(16))) float f32x16;
typedef __attribute__((ext_vector_type(2))) int i32x2;
typedef __attribute__((ext_vector_type(4))) u32 u32x4;
typedef const __attribute__((address_space(1))) void* gptr_t;
typedef __attribute__((address_space(3))) void* sptr_t;

__device__ __forceinline__ u16 f2b(float f) {
  __hip_bfloat16 h = __float2bfloat16(f);
  return __builtin_bit_cast(u16, h);
}

// v_cvt_pk_bf16_f32: lo -> bits[15:0], hi -> bits[31:16]
__device__ __forceinline__ u32 cvtpk(float lo, float hi) {
  u32 r;
  asm volatile("v_cvt_pk_bf16_f32 %0, %1, %2" : "=v"(r) : "v"(lo), "v"(hi));
  return r;
}

// ---------------- fp32 -> bf16 convert (vectorized) ----------------
__global__ __launch_bounds__(256) void cvt_kernel(const float* __restrict__ src,
                                                  u16* __restrict__ dst, int n4) {
  int i = blockIdx.x * blockDim.x + threadIdx.x;
  int stride = gridDim.x * blockDim.x;
  for (; i < n4; i += stride) {
    float4 f = ((const float4*)src)[i];
    ushort4 o;
    o.x = f2b(f.x); o.y = f2b(f.y); o.z = f2b(f.z); o.w = f2b(f.w);
    ((ushort4*)dst)[i] = o;
  }
}

// ---------------- transpose + convert both weights (merged) ----------------
// y < 48: W_attn[1024][3072] -> Wat[3072][1024];  y >= 48: W_proj -> Wpt.
__global__ __launch_bounds__(256) void tr_cvt2(const float* __restrict__ Wa,
                                               u16* __restrict__ Wat,
                                               const float* __restrict__ Wp,
                                               u16* __restrict__ Wpt) {
  __shared__ u16 tile[64][72];   // +8 pad
  const bool attn = (blockIdx.y < 48);
  const float* src = attn ? Wa : Wp;
  u16* dst = attn ? Wat : Wpt;
  const int N = attn ? N3_ : C_;
  int k0 = blockIdx.x * 64, n0 = (attn ? blockIdx.y : blockIdx.y - 48) * 64;
  #pragma unroll
  for (int t = 0; t < 16; ++t) {
    int idx = threadIdx.x + t * 256;
    int r = idx >> 6, c = idx & 63;
    tile[r][c] = f2b(src[(size_t)(k0 + r) * N + n0 + c]);
  }
  __syncthreads();
  #pragma unroll
  for (int t = 0; t < 16; ++t) {
    int idx = threadIdx.x + t * 256;
    int r = idx >> 6, c = idx & 63;       // r = local n, c = local k
    dst[(size_t)(n0 + r) * C_ + k0 + c] = tile[c][r];
  }
}

// ---------------- GEMM: C[M][N] = A[M][K] * Bt[N][K]^T + bias ----------------
// BM=128 x BN=128, BK=64, 4 waves (2x2), per-wave 64x64 (acc 4x4).
// 2-buffer ping-pong, ONE barrier per K-step (halves sync events vs BK=32):
// at iter t, stage(t+1) (8 gloads/thread) issues at the TOP into buf^1 --
// whose reads finished before the PREVIOUS barrier, so the async LDS writes
// are race-free. Then 16 frag ds_reads (compiler-scheduled lgkmcnt), 32 MFMA
// in two k-half clusters, vmcnt(0) (issued ~full iter earlier -> residual
// wait only) + single s_barrier. Granule-XOR swizzle mod 8: global granule
// gk stored at LDS granule gk^(row&7); read fetches (4h+lk)^(r&7).
// EPI 0: scatter to q (scaled) / k / v^T.  EPI 1: fp32 out [M][N].
template <int EPI>
__global__ __launch_bounds__(256, 2) void gemm_bt(const u16* __restrict__ A,
                                                  const u16* __restrict__ Bt,
                                                  const float* __restrict__ bias,
                                                  int K, int N,
                                                  u16* __restrict__ out_qkv,
                                                  float* __restrict__ out_f) {
  __shared__ __align__(16) u16 As[2][128 * 64];
  __shared__ __align__(16) u16 Bs[2][128 * 64];
  const int tid = threadIdx.x;
  const int wave = tid >> 6, lane = tid & 63;
  const int lr = lane & 15, lk = lane >> 4;

  const int m0 = blockIdx.x * 128, n0 = blockIdx.y * 128;
  const int wr = (wave >> 1) * 64, wc = (wave & 1) * 64;

  f32x4 acc[4][4] = {};

  auto stage = [&](int buf, int it) {            // 8 gloads/thread (4 A + 4 B)
    const int kt = it * 64;
    #pragma unroll
    for (int i = 0; i < 4; ++i) {
      int ch = i * 256 + tid;                    // A: 1024 chunks (128r x 8g)
      int row = ch >> 3;
      int gsrc = (ch & 7) ^ (row & 7);
      __builtin_amdgcn_global_load_lds((gptr_t)(A + (size_t)(m0 + row) * K + kt + gsrc * 8),
                                       (sptr_t)(&As[buf][ch * 8]), 16, 0, 0);
    }
    #pragma unroll
    for (int i = 0; i < 4; ++i) {
      int ch = i * 256 + tid;                    // B: 1024 chunks
      int row = ch >> 3;
      int gsrc = (ch & 7) ^ (row & 7);
      __builtin_amdgcn_global_load_lds((gptr_t)(Bt + (size_t)(n0 + row) * K + kt + gsrc * 8),
                                       (sptr_t)(&Bs[buf][ch * 8]), 16, 0, 0);
    }
  };

  const int KI = K / 64;                         // 16 iters (K=1024)
  stage(0, 0);
  asm volatile("s_waitcnt vmcnt(0)" ::: "memory");
  __builtin_amdgcn_s_barrier();

  for (int it = 0; it < KI; ++it) {
    const int cur = it & 1;
    if (it + 1 < KI) stage(cur ^ 1, it + 1);     // into buffer freed 1 barrier ago

    // ---- two k-half clusters: read 8 frags, 16 MFMA each ----
    #pragma unroll
    for (int h = 0; h < 2; ++h) {
      bf16x8 af[4], bfr[4];
      #pragma unroll
      for (int mi = 0; mi < 4; ++mi) {
        int r = wr + mi * 16 + lr;
        af[mi] = *(const bf16x8*)(&As[cur][r * 64 + (((4 * h + lk) ^ (r & 7)) << 3)]);
      }
      #pragma unroll
      for (int ni = 0; ni < 4; ++ni) {
        int r = wc + ni * 16 + lr;
        bfr[ni] = *(const bf16x8*)(&Bs[cur][r * 64 + (((4 * h + lk) ^ (r & 7)) << 3)]);
      }
      __builtin_amdgcn_s_setprio(1);
      #pragma unroll
      for (int mi = 0; mi < 4; ++mi)
        #pragma unroll
        for (int ni = 0; ni < 4; ++ni)
          acc[mi][ni] = __builtin_amdgcn_mfma_f32_16x16x32_bf16(af[mi], bfr[ni], acc[mi][ni], 0, 0, 0);
      __builtin_amdgcn_s_setprio(0);
    }

    // ---- tile boundary: t+1's loads were issued a full iter ago ----
    asm volatile("s_waitcnt vmcnt(0)" ::: "memory");
    __builtin_amdgcn_s_barrier();
  }

  if (EPI == 0) {
    const int sel = (n0 >> 10);                   // whole block same q/k/v segment
    #pragma unroll
    for (int mi = 0; mi < 4; ++mi) {
      #pragma unroll
      for (int ni = 0; ni < 4; ++ni) {
        int m = m0 + wr + mi * 16 + lk * 4;       // +j
        int n = n0 + wc + ni * 16 + lr;
        int rem = n & 1023, h = rem >> 6, d = rem & 63;
        int b = m >> 11, t = m & 2047;
        if (sel == 2) {                           // v^T: t contiguous -> ushort4
          ushort4 st;
          #pragma unroll
          for (int j = 0; j < 4; ++j)
            ((u16*)&st)[j] = f2b(acc[mi][ni][j] + bias[n]);
          *(ushort4*)(out_qkv + 2 * (size_t)QKVSZ +
                      (((size_t)(b * H_ + h) * HD_ + d) * T_ + t)) = st;
        } else {
          #pragma unroll
          for (int j = 0; j < 4; ++j) {
            float val = acc[mi][ni][j] + bias[n];
            if (sel == 0) val *= QSCALE;
            out_qkv[(size_t)sel * QKVSZ +
                    (((size_t)(b * H_ + h) * T_ + (t + j)) * HD_ + d)] = f2b(val);
          }
        }
      }
    }
  } else {
    #pragma unroll
    for (int mi = 0; mi < 4; ++mi)
      #pragma unroll
      for (int ni = 0; ni < 4; ++ni)
        #pragma unroll
        for (int j = 0; j < 4; ++j) {
          int m = m0 + wr + mi * 16 + lk * 4 + j;
          int n = n0 + wc + ni * 16 + lr;
          out_f[(size_t)m * C_ + n] = acc[mi][ni][j] + bias[n];
        }
  }
}

// ---------------- causal flash attention ----------------
// 256 threads = 4 waves; q-tile 128 (wave w owns q-rows [BQ+32w, BQ+32w+32)).
// grid (bh=64, 16 q-tiles) = 1024 blocks, heavy-first -> 4 blocks/CU ALL
// resident = 16 waves/CU. K/V staged once per block serves 4 waves.
// 32x32x16 MFMAs, swapped S^T = mfma(K,Q). Softmax per-lane: raw v_exp_f32,
// shfl_xor(32) reduce. P in registers via cvt_pk + permlane32_swap.
// O^T = mfma(Vt, P). Granule swizzle (row&7)^((row>>3)&3) on BOTH sides.
__global__ __launch_bounds__(256, 4) void attn_k(const u16* __restrict__ q,
                                                 const u16* __restrict__ k,
                                                 const u16* __restrict__ vt,
                                                 u16* __restrict__ y) {
  __shared__ __align__(16) u16 Ks[2][64 * 64];
  __shared__ __align__(16) u16 Vs[2][64 * 64];
  const int tid = threadIdx.x;
  const int wave = tid >> 6, lane = tid & 63;
  const int hi = lane >> 5, lq = lane & 31;
  const int qtb = gridDim.y - 1 - blockIdx.y;    // 15..0, heavy first
  const int bh = blockIdx.x;                     // fastest dim -> XCD spread
  const size_t koff = (size_t)bh * T_ * HD_;     // q,k: [bh][t][d]
  const size_t voff = (size_t)bh * HD_ * T_;     // vt:  [bh][d][t]
  const int qrow = qtb * 128 + 32 * wave + lq;   // this lane's q row (global)
  const int sw = (lq & 7) ^ ((lq >> 3) & 3);     // read-granule swizzle (row=32kh+lq)

  // Q B-frags (pre-scaled by 0.125*log2e): qf[c] = Q[qrow][16c+8hi .. +8]
  bf16x8 qf[4];
  #pragma unroll
  for (int c = 0; c < 4; ++c)
    qf[c] = *(const bf16x8*)(q + koff + (size_t)qrow * HD_ + 16 * c + 8 * hi);

  f32x16 o[2] = {};                              // [dh]: O^T rows 32dh..
  float mrun = -1e30f, lsum = 0.f;

  auto stage = [&](int buf, int kt) {
    const u16* kb = k + koff + (size_t)kt * 64 * HD_;
    const u16* vb = vt + voff + (size_t)kt * 64;
    #pragma unroll
    for (int j = 0; j < 2; ++j) {
      int cb = j * 256 + wave * 64;              // wave-uniform chunk base
      int ch = cb + lane;
      int row = ch >> 3, gg = ch & 7;
      int src = gg ^ (row & 7) ^ ((row >> 3) & 3);   // pre-swizzled source
      __builtin_amdgcn_global_load_lds((gptr_t)(kb + row * HD_ + src * 8),
                                       (sptr_t)(&Ks[buf][cb * 8]), 16, 0, 0);
      __builtin_amdgcn_global_load_lds((gptr_t)(vb + (size_t)row * T_ + src * 8),
                                       (sptr_t)(&Vs[buf][cb * 8]), 16, 0, 0);
    }
  };

  const int nt = 2 * qtb + 2;
  stage(0, 0);
  __syncthreads();

  for (int kt = 0; kt < nt; ++kt) {
    const int cur = kt & 1;
    if (kt + 1 < nt) stage(cur ^ 1, kt + 1);
    const bool active = (kt <= 2 * qtb + (wave >> 1));
    if (active) {
      const bool dia = (kt == 2 * qtb + (wave >> 1));
      const bool skip1 = dia && ((wave & 1) == 0);   // kh=1 fully masked
      const u16* Kb = &Ks[cur][0];
      const u16* Vb = &Vs[cur][0];

      // ---- S^T = K Q^T ----
      f32x16 s[2] = {};
      __builtin_amdgcn_s_setprio(1);
      #pragma unroll
      for (int c = 0; c < 4; ++c) {
        #pragma unroll
        for (int kh = 0; kh < 2; ++kh) {
          if (kh == 1 && skip1) continue;
          int row = 32 * kh + lq;
          bf16x8 kf = *(const bf16x8*)(Kb + row * 64 + (((2 * c + hi) ^ sw) << 3));
          s[kh] = __builtin_amdgcn_mfma_f32_32x32x16_bf16(kf, qf[c], s[kh], 0, 0, 0);
        }
      }
      __builtin_amdgcn_s_setprio(0);

      if (dia) {
        #pragma unroll
        for (int rr = 0; rr < 16; ++rr) {
          int kg = 64 * kt + 4 * hi + (rr & 3) + 8 * (rr >> 2);
          if ((wave & 1) == 0) { if (kg > qrow)      s[0][rr] = -1e30f; }
          else                 { if (kg + 32 > qrow) s[1][rr] = -1e30f; }
        }
      }

      // ---- online softmax (lane and lane^32 share a q-row) ----
      float g0, g1, g2, g3;
      {
        const f32x16& a = s[0];
        g0 = fmaxf(fmaxf(a[0], a[1]),   fmaxf(a[2], a[3]));
        g1 = fmaxf(fmaxf(a[4], a[5]),   fmaxf(a[6], a[7]));
        g2 = fmaxf(fmaxf(a[8], a[9]),   fmaxf(a[10], a[11]));
        g3 = fmaxf(fmaxf(a[12], a[13]), fmaxf(a[14], a[15]));
      }
      if (!skip1) {
        const f32x16& a = s[1];
        g0 = fmaxf(g0, fmaxf(fmaxf(a[0], a[1]),   fmaxf(a[2], a[3])));
        g1 = fmaxf(g1, fmaxf(fmaxf(a[4], a[5]),   fmaxf(a[6], a[7])));
        g2 = fmaxf(g2, fmaxf(fmaxf(a[8], a[9]),   fmaxf(a[10], a[11])));
        g3 = fmaxf(g3, fmaxf(fmaxf(a[12], a[13]), fmaxf(a[14], a[15])));
      }
      float tm = fmaxf(fmaxf(g0, g1), fmaxf(g2, g3));
      tm = fmaxf(tm, __shfl_xor(tm, 32));
      if (__any(tm > mrun + 8.f)) {              // defer-max (T13)
        float mn = fmaxf(mrun, tm);
        float al = __builtin_amdgcn_exp2f(mrun - mn);
        lsum *= al;
        o[0] *= al;
        o[1] *= al;
        mrun = mn;
      }
      float rs = 0.f;
      #pragma unroll
      for (int kh = 0; kh < 2; ++kh) {
        if (kh == 1 && skip1) continue;
        #pragma unroll
        for (int rr = 0; rr < 16; ++rr) {
          float p = __builtin_amdgcn_exp2f(s[kh][rr] - mrun);
          s[kh][rr] = p;
          rs += p;
        }
      }
      rs += __shfl_xor(rs, 32);
      lsum += rs;

      // ---- PV: O^T[d][q] += Vt P (P assembled in-register) ----
      #pragma unroll
      for (int kh = 0; kh < 2; ++kh) {
        if (kh == 1 && skip1) continue;
        bf16x8 pf[2];
        #pragma unroll
        for (int ct = 0; ct < 2; ++ct) {
          u32 A0 = cvtpk(s[kh][8 * ct + 0], s[kh][8 * ct + 1]);
          u32 A1 = cvtpk(s[kh][8 * ct + 2], s[kh][8 * ct + 3]);
          u32 B0 = cvtpk(s[kh][8 * ct + 4], s[kh][8 * ct + 5]);
          u32 B1 = cvtpk(s[kh][8 * ct + 6], s[kh][8 * ct + 7]);
          i32x2 r0 = __builtin_amdgcn_permlane32_swap((int)A0, (int)B0, false, false);
          i32x2 r1 = __builtin_amdgcn_permlane32_swap((int)A1, (int)B1, false, false);
          u32x4 w = {(u32)r0[0], (u32)r1[0], (u32)r0[1], (u32)r1[1]};
          pf[ct] = __builtin_bit_cast(bf16x8, w);
        }
        __builtin_amdgcn_s_setprio(1);
        #pragma unroll
        for (int ct = 0; ct < 2; ++ct)
          #pragma unroll
          for (int dh = 0; dh < 2; ++dh) {
            int row = 32 * dh + lq;
            bf16x8 vf = *(const bf16x8*)(Vb + row * 64 + (((4 * kh + 2 * ct + hi) ^ sw) << 3));
            o[dh] = __builtin_amdgcn_mfma_f32_32x32x16_bf16(vf, pf[ct], o[dh], 0, 0, 0);
          }
        __builtin_amdgcn_s_setprio(0);
      }
    }
    __syncthreads();
  }

  // ---- epilogue: y[b,t,h*64+d] = O^T[d][q] / l ----
  const int b = bh >> 4, h = bh & 15;
  float li = 1.0f / lsum;
  u16* yrow = y + (size_t)(b * T_ + qrow) * C_ + h * 64;
  #pragma unroll
  for (int dh = 0; dh < 2; ++dh)
    #pragma unroll
    for (int u = 0; u < 4; ++u) {
      ushort4 st;
      st.x = f2b(o[dh][4 * u + 0] * li);
      st.y = f2b(o[dh][4 * u + 1] * li);
      st.z = f2b(o[dh][4 * u + 2] * li);
      st.w = f2b(o[dh][4 * u + 3] * li);
      *(ushort4*)(yrow + 32 * dh + 8 * u + 4 * hi) = st;
    }
}

extern "C" void kernel_launch(void* const* d_in, const int* in_sizes, int n_in,
                              void* d_out, int out_size, void* d_ws, size_t ws_size,
                              hipStream_t stream) {
  const float* x      = (const float*)d_in[0];
  const float* W_attn = (const float*)d_in[1];
  const float* b_attn = (const float*)d_in[2];
  const float* W_proj = (const float*)d_in[3];
  const float* b_proj = (const float*)d_in[4];
  float* out = (float*)d_out;

  u16* ws = (u16*)d_ws;
  u16* xb  = ws;
  u16* Wat = xb + (size_t)M_ * C_;
  u16* Wpt = Wat + (size_t)N3_ * C_;
  u16* qkv = Wpt + (size_t)C_ * C_;
  u16* y   = qkv + (size_t)3 * QKVSZ;

  cvt_kernel<<<2048, 256, 0, stream>>>(x, xb, M_ * C_ / 4);
  tr_cvt2<<<dim3(C_ / 64, 64), 256, 0, stream>>>(W_attn, Wat, W_proj, Wpt);
  gemm_bt<0><<<dim3(M_ / 128, N3_ / 128), 256, 0, stream>>>(xb, Wat, b_attn, C_, N3_, qkv, nullptr);
  attn_k<<<dim3(B_ * H_, T_ / 128), 256, 0, stream>>>(qkv, qkv + QKVSZ, qkv + 2 * QKVSZ, y);
  gemm_bt<1><<<dim3(M_ / 128, C_ / 128), 256, 0, stream>>>(y, Wpt, b_proj, C_, C_, nullptr, out);
}